// Round 4
// baseline (534.982 us; speedup 1.0000x reference)
//
#include <hip/hip_runtime.h>

#define NN 50000
#define NE 500000
#define HD 128
#define HD2 256
#define NL 4
#define NG 1000

constexpr float MSG_EPS = 1e-7f;
constexpr float LNEPS   = 1e-5f;
constexpr float LOG2E   = 1.44269504088896f;

typedef float  f32x4  __attribute__((ext_vector_type(4)));
typedef __bf16 bf16x8 __attribute__((ext_vector_type(8)));

__device__ __forceinline__ unsigned short f2b(float f) {
    unsigned int u = __float_as_uint(f);
    unsigned int r = u + 0x7FFFu + ((u >> 16) & 1u);
    return (unsigned short)(r >> 16);
}
__device__ __forceinline__ float b2f(unsigned short h) {
    return __uint_as_float(((unsigned int)h) << 16);
}
__device__ __forceinline__ unsigned int pack2(float a, float b) {
    return (unsigned int)f2b(a) | ((unsigned int)f2b(b) << 16);
}

// ---------------- node encoder: z0 = bf16(x @ Wn + bn), grid-stride ----------------
__global__ __launch_bounds__(256) void k_encode_nodes(const float* __restrict__ x,
                                                      const float* __restrict__ W,
                                                      const float* __restrict__ b,
                                                      unsigned short* __restrict__ zb) {
    int t0 = blockIdx.x * 256 + threadIdx.x;
    int c = t0 & 127;  // constant across the stride loop (stride % 128 == 0)
    float wc[9];
#pragma unroll
    for (int k = 0; k < 9; k++) wc[k] = W[k * HD + c];
    float bc = b[c];
    for (int idx = t0; idx < NN * HD; idx += gridDim.x * 256) {
        int n = idx >> 7;
        float acc = bc;
#pragma unroll
        for (int k = 0; k < 9; k++) acc = fmaf(x[n * 9 + k], wc[k], acc);
        zb[idx] = f2b(acc);
    }
}

// ---------------- weight prep: fp32 -> bf16 transposed ----------------
__global__ void k_prep(const float* __restrict__ W1, const float* __restrict__ W2,
                       unsigned short* __restrict__ W1T, unsigned short* __restrict__ W2T) {
    int idx = blockIdx.x * 256 + threadIdx.x;  // 131072 total
    {
        int k = idx & 127, n = (idx >> 7) & 255, l = idx >> 15;
        W1T[idx] = f2b(W1[(l * 128 + k) * 256 + n]);
    }
    {
        int k = idx & 255, n = (idx >> 8) & 127, l = idx >> 15;
        W2T[idx] = f2b(W2[(l * 256 + k) * 128 + n]);
    }
}

// ---------------- CSR build ----------------
__global__ void k_hist(const int* __restrict__ dst, int* __restrict__ counts) {
    int e = blockIdx.x * blockDim.x + threadIdx.x;
    if (e < NE) atomicAdd(&counts[dst[e]], 1);
}

#define SCAN_B 512
__global__ void k_scan1(const int* __restrict__ counts, int* __restrict__ incl,
                        int* __restrict__ bsum) {
    __shared__ int s[SCAN_B];
    int i = blockIdx.x * SCAN_B + threadIdx.x;
    int v = (i < NN) ? counts[i] : 0;
    s[threadIdx.x] = v;
    __syncthreads();
    for (int off = 1; off < SCAN_B; off <<= 1) {
        int t = (threadIdx.x >= off) ? s[threadIdx.x - off] : 0;
        __syncthreads();
        s[threadIdx.x] += t;
        __syncthreads();
    }
    if (i < NN) incl[i] = s[threadIdx.x];
    if (threadIdx.x == SCAN_B - 1) bsum[blockIdx.x] = s[threadIdx.x];
}

__global__ void k_scan2(const int* __restrict__ bsum, int* __restrict__ boff, int nb) {
    __shared__ int s[128];
    int v = (threadIdx.x < nb) ? bsum[threadIdx.x] : 0;
    s[threadIdx.x] = v;
    __syncthreads();
    for (int off = 1; off < 128; off <<= 1) {
        int t = (threadIdx.x >= off) ? s[threadIdx.x - off] : 0;
        __syncthreads();
        s[threadIdx.x] += t;
        __syncthreads();
    }
    if (threadIdx.x < nb) boff[threadIdx.x] = s[threadIdx.x] - v;  // exclusive
}

__global__ void k_scan3(const int* __restrict__ incl, const int* __restrict__ boff,
                        int* __restrict__ row_start) {
    int i = blockIdx.x * SCAN_B + threadIdx.x;
    if (i < NN) row_start[i + 1] = incl[i] + boff[blockIdx.x];
    if (i == 0) row_start[0] = 0;
}

// pack {attr0, attr1, attr2, src<<6} per CSR slot (src premultiplied: z-row offset
// in uints, so the gather address is a single 32-bit add per edge)
__global__ void k_scatter(const int* __restrict__ src, const int* __restrict__ dst,
                          const float* __restrict__ eattr, const int* __restrict__ row_start,
                          int* __restrict__ cursor, float4* __restrict__ aperm) {
    int e = blockIdx.x * blockDim.x + threadIdx.x;
    if (e >= NE) return;
    int d = dst[e];
    int p = row_start[d] + atomicAdd(&cursor[d], 1);
    float4 v;
    v.x = eattr[e * 3 + 0];
    v.y = eattr[e * 3 + 1];
    v.z = eattr[e * 3 + 2];
    v.w = __int_as_float(src[e] << 6);
    aperm[p] = v;
}

// ---- per-edge softmax-agg accumulate (2 channels/lane); ktv = t*log2(e);
// invalid edges contribute exactly 0 (ex,ey forced to 0) ----
__device__ __forceinline__ void edge_acc2m(float4 a, unsigned int zz, float2 w0, float2 w1,
                                           float2 w2, float2 bb, float ktv, float& num0,
                                           float& num1, float& wm0, float& wm1, bool valid) {
    float zx = b2f((unsigned short)zz), zy = b2f((unsigned short)(zz >> 16));
    float eax = fmaf(a.x, w0.x, fmaf(a.y, w1.x, fmaf(a.z, w2.x, bb.x)));
    float eay = fmaf(a.x, w0.y, fmaf(a.y, w1.y, fmaf(a.z, w2.y, bb.y)));
    float mx = fmaxf(zx + eax, 0.f) + MSG_EPS;
    float my = fmaxf(zy + eay, 0.f) + MSG_EPS;
    float ex = valid ? exp2f(ktv * mx) : 0.f;
    float ey = valid ? exp2f(ktv * my) : 0.f;
    num0 += ex;
    num1 += ey;
    wm0 = fmaf(mx, ex, wm0);
    wm1 = fmaf(my, ey, wm1);
}

// ---------------- softmax aggregation: one wave per node, 2 channels/lane ----------
// 8-deep chunked gather pipeline: edges are processed in chunks of 8 with CLAMPED
// loads (tail duplicates masked in the accumulate -> no divergent drain loops).
// Chunk 0's 8 gathers issue back-to-back; in steady state the next chunk's aperm
// loads are in flight during the current chunk's accumulate. Typical node (deg~10)
// exposes ~1 gather latency instead of ~2.5.
__global__ __launch_bounds__(256) void k_aggregate(const unsigned short* __restrict__ zbin,
                                                   const float4* __restrict__ aperm,
                                                   const int* __restrict__ row_start,
                                                   const float* __restrict__ We,
                                                   const float* __restrict__ be,
                                                   const float* __restrict__ t, int layer,
                                                   unsigned int* __restrict__ outb) {
    int w = threadIdx.x >> 6, lane = threadIdx.x & 63;
    int n = blockIdx.x * 4 + w;
    if (n >= NN) return;
    int c = lane * 2;
    float2 w0 = *(const float2*)&We[c];
    float2 w1 = *(const float2*)&We[HD + c];
    float2 w2 = *(const float2*)&We[2 * HD + c];
    float2 bb = *(const float2*)&be[c];
    float ktv = t[layer] * LOG2E;
    int s0 = row_start[n], s1 = row_start[n + 1];
    const unsigned int* z32 = (const unsigned int*)zbin;
    unsigned int zn = z32[(size_t)n * 64 + lane];  // self row, early issue
    float num0 = 0.f, num1 = 0.f, wm0 = 0.f, wm1 = 0.f;
    if (s1 > s0) {
        float4 A[8];
        unsigned int g[8];
#pragma unroll
        for (int j = 0; j < 8; j++) A[j] = aperm[min(s0 + j, s1 - 1)];
#pragma unroll
        for (int j = 0; j < 8; j++)
            g[j] = z32[(unsigned int)__float_as_int(A[j].w) + lane];
        int p = s0 + 8;
        for (; p < s1; p += 8) {
            float4 B[8];
#pragma unroll
            for (int j = 0; j < 8; j++) B[j] = aperm[min(p + j, s1 - 1)];
            // chunk at p-8 is fully valid (p-1 < s1)
#pragma unroll
            for (int j = 0; j < 8; j++)
                edge_acc2m(A[j], g[j], w0, w1, w2, bb, ktv, num0, num1, wm0, wm1, true);
#pragma unroll
            for (int j = 0; j < 8; j++) A[j] = B[j];
#pragma unroll
            for (int j = 0; j < 8; j++)
                g[j] = z32[(unsigned int)__float_as_int(A[j].w) + lane];
        }
        int rem = s1 - (p - 8);  // 1..8 valid entries in the final chunk
#pragma unroll
        for (int j = 0; j < 8; j++)
            edge_acc2m(A[j], g[j], w0, w1, w2, bb, ktv, num0, num1, wm0, wm1, j < rem);
    }
    float ox = ((s1 > s0) ? (wm0 / num0) : 0.f) + b2f((unsigned short)zn);
    float oy = ((s1 > s0) ? (wm1 / num1) : 0.f) + b2f((unsigned short)(zn >> 16));
    outb[(size_t)n * 64 + lane] = pack2(ox, oy);
}

// ---------------- fused MFMA MLP + next-layer LN+relu ----------------
// hnew = (add? h : 0) + relu(LN(A@W1+b1))@W2+b2 ; h=bf16(hnew); zb=bf16(relu(LN_next(hnew)))
// BM=32, 4 waves. In-register LN1 stats (st1 LDS exchange). Full A tile + residual h
// rows + epilogue LN params prefetched at entry. (Verified round-3 version, unchanged.)
#define BM 32
#define HS_LD 264  // bf16 row stride (256+8)
#define HT_LD 136  // bf16 row stride (128+8); as uint: 68

__global__ __launch_bounds__(256) void k_mlp(const unsigned short* __restrict__ outb,
                                             const unsigned short* __restrict__ W1T,
                                             const float* __restrict__ b1l,
                                             const float* __restrict__ lgl,
                                             const float* __restrict__ lbl,
                                             const unsigned short* __restrict__ W2T,
                                             const float* __restrict__ b2l,
                                             unsigned short* __restrict__ h,
                                             const float* __restrict__ gn,
                                             const float* __restrict__ bn,
                                             unsigned short* __restrict__ zb,
                                             int add_residual, int store_h) {
    __shared__ __align__(16) unsigned short Hs[BM * HS_LD];  // 16896 B
    __shared__ __align__(16) unsigned short Ht[BM * HT_LD];  // 8704 B
    __shared__ __align__(16) float2 st1[2][16][4];           // 1024 B

    int nb = blockIdx.x * BM;
    int tid = threadIdx.x;
    int w = tid >> 6, lane = tid & 63, q = lane >> 4, i = lane & 15;

    // ---- full A prefetch: all 8 fragments issue NOW (32 VGPR) ----
    bf16x8 areg[2][4];
#pragma unroll
    for (int rt = 0; rt < 2; rt++) {
        int row = nb + rt * 16 + i;
#pragma unroll
        for (int ks = 0; ks < 4; ks++)
            areg[rt][ks] = (row < NN)
                               ? *(const bf16x8*)&outb[(size_t)row * HD + ks * 32 + q * 8]
                               : (bf16x8)(__bf16)0.f;
    }

    // ---- epilogue prefetch: residual h rows + final-LN params ----
    unsigned int hv[8];
    const unsigned int* h32c = (const unsigned int*)h;
    if (add_residual) {
#pragma unroll
        for (int it = 0; it < 8; it++) {
            int row = nb + w + it * 4;
            hv[it] = (row < NN) ? h32c[(size_t)row * 64 + lane] : 0u;
        }
    } else {
#pragma unroll
        for (int it = 0; it < 8; it++) hv[it] = 0u;
    }
    float2 gg = *(const float2*)&gn[lane * 2];
    float2 cc = *(const float2*)&bn[lane * 2];

    // ---- GEMM1: 32x256, K=128; A in registers, B 1-step lookahead ----
    f32x4 acc[2][4];
#pragma unroll
    for (int rt = 0; rt < 2; rt++)
#pragma unroll
        for (int ct = 0; ct < 4; ct++) acc[rt][ct] = (f32x4){0.f, 0.f, 0.f, 0.f};

    bf16x8 bcur[4];
#pragma unroll
    for (int ct = 0; ct < 4; ct++)
        bcur[ct] = *(const bf16x8*)&W1T[(w * 64 + ct * 16 + i) * HD + q * 8];

#pragma unroll
    for (int ks = 0; ks < 4; ks++) {
        bf16x8 bnxt[4];
        if (ks < 3) {
#pragma unroll
            for (int ct = 0; ct < 4; ct++)
                bnxt[ct] =
                    *(const bf16x8*)&W1T[(w * 64 + ct * 16 + i) * HD + (ks + 1) * 32 + q * 8];
        }
#pragma unroll
        for (int rt = 0; rt < 2; rt++)
#pragma unroll
            for (int ct = 0; ct < 4; ct++)
                acc[rt][ct] = __builtin_amdgcn_mfma_f32_16x16x32_bf16(areg[rt][ks], bcur[ct],
                                                                     acc[rt][ct], 0, 0, 0);
        if (ks < 3) {
#pragma unroll
            for (int ct = 0; ct < 4; ct++) bcur[ct] = bnxt[ct];
        }
    }

    // ---- +b1 ----
#pragma unroll
    for (int ct = 0; ct < 4; ct++) {
        float bb = b1l[w * 64 + ct * 16 + i];
#pragma unroll
        for (int rt = 0; rt < 2; rt++)
#pragma unroll
            for (int r = 0; r < 4; r++) acc[rt][ct][r] += bb;
    }

    // ---- LN(256) stats in-register + cross-wave exchange ----
    {
        float sv[2][4], qv[2][4];
#pragma unroll
        for (int rt = 0; rt < 2; rt++)
#pragma unroll
            for (int r = 0; r < 4; r++) {
                float s = acc[rt][0][r] + acc[rt][1][r] + acc[rt][2][r] + acc[rt][3][r];
                float sq = 0.f;
#pragma unroll
                for (int ct = 0; ct < 4; ct++) sq = fmaf(acc[rt][ct][r], acc[rt][ct][r], sq);
                sv[rt][r] = s;
                qv[rt][r] = sq;
            }
#pragma unroll
        for (int m = 1; m <= 8; m <<= 1)
#pragma unroll
            for (int rt = 0; rt < 2; rt++)
#pragma unroll
                for (int r = 0; r < 4; r++) {
                    sv[rt][r] += __shfl_xor(sv[rt][r], m);
                    qv[rt][r] += __shfl_xor(qv[rt][r], m);
                }
        if (i == 0) {
#pragma unroll
            for (int rt = 0; rt < 2; rt++)
#pragma unroll
                for (int r = 0; r < 4; r++)
                    st1[rt][q * 4 + r][w] = make_float2(sv[rt][r], qv[rt][r]);
        }
    }
    __syncthreads();

    {
        float mu[2][4], inv[2][4];
#pragma unroll
        for (int rt = 0; rt < 2; rt++)
#pragma unroll
            for (int r = 0; r < 4; r++) {
                const float4* sp = (const float4*)&st1[rt][q * 4 + r][0];
                float4 a = sp[0], b = sp[1];
                float S = a.x + a.z + b.x + b.z;
                float Q = a.y + a.w + b.y + b.w;
                float m_ = S * (1.f / 256.f);
                float v_ = Q * (1.f / 256.f) - m_ * m_;
                mu[rt][r] = m_;
                inv[rt][r] = rsqrtf(v_ + LNEPS);
            }
#pragma unroll
        for (int ct = 0; ct < 4; ct++) {
            float g = lgl[w * 64 + ct * 16 + i];
            float c = lbl[w * 64 + ct * 16 + i];
#pragma unroll
            for (int rt = 0; rt < 2; rt++)
#pragma unroll
                for (int r = 0; r < 4; r++) {
                    float v =
                        fmaxf(fmaf((acc[rt][ct][r] - mu[rt][r]) * inv[rt][r], g, c), 0.f);
                    Hs[(rt * 16 + q * 4 + r) * HS_LD + w * 64 + ct * 16 + i] = f2b(v);
                }
        }
    }
    __syncthreads();

    // ---- GEMM2: 32x128, K=256; A from Hs, 1-step lookahead ----
    f32x4 acc2[2][2];
#pragma unroll
    for (int rt = 0; rt < 2; rt++)
#pragma unroll
        for (int ct = 0; ct < 2; ct++) acc2[rt][ct] = (f32x4){0.f, 0.f, 0.f, 0.f};

    bf16x8 hc[2], bc[2];
#pragma unroll
    for (int rt = 0; rt < 2; rt++) hc[rt] = *(const bf16x8*)&Hs[(rt * 16 + i) * HS_LD + q * 8];
#pragma unroll
    for (int ct = 0; ct < 2; ct++)
        bc[ct] = *(const bf16x8*)&W2T[(w * 32 + ct * 16 + i) * HD2 + q * 8];

#pragma unroll
    for (int ks = 0; ks < 8; ks++) {
        bf16x8 hn[2], bn2[2];
        if (ks < 7) {
#pragma unroll
            for (int rt = 0; rt < 2; rt++)
                hn[rt] = *(const bf16x8*)&Hs[(rt * 16 + i) * HS_LD + (ks + 1) * 32 + q * 8];
#pragma unroll
            for (int ct = 0; ct < 2; ct++)
                bn2[ct] =
                    *(const bf16x8*)&W2T[(w * 32 + ct * 16 + i) * HD2 + (ks + 1) * 32 + q * 8];
        }
#pragma unroll
        for (int rt = 0; rt < 2; rt++)
#pragma unroll
            for (int ct = 0; ct < 2; ct++)
                acc2[rt][ct] = __builtin_amdgcn_mfma_f32_16x16x32_bf16(hc[rt], bc[ct],
                                                                      acc2[rt][ct], 0, 0, 0);
        if (ks < 7) {
#pragma unroll
            for (int rt = 0; rt < 2; rt++) hc[rt] = hn[rt];
#pragma unroll
            for (int ct = 0; ct < 2; ct++) bc[ct] = bn2[ct];
        }
    }

    // ---- conv-out (+b2) -> bf16 LDS tile Ht (C-layout scatter; LDS absorbs it) ----
#pragma unroll
    for (int ct = 0; ct < 2; ct++) {
        float bb = b2l[w * 32 + ct * 16 + i];
#pragma unroll
        for (int rt = 0; rt < 2; rt++)
#pragma unroll
            for (int r = 0; r < 4; r++)
                Ht[(rt * 16 + q * 4 + r) * HT_LD + w * 32 + ct * 16 + i] =
                    f2b(acc2[rt][ct][r] + bb);
    }
    __syncthreads();

    // ---- row-wise COALESCED epilogue: residual (pre-fetched), h store, LN(128), zb ----
    {
        const unsigned int* Ht32 = (const unsigned int*)Ht;
        unsigned int* h32 = (unsigned int*)h;
        unsigned int* zb32 = (unsigned int*)zb;
#pragma unroll
        for (int it = 0; it < 8; it++) {
            int rr = w + it * 4;
            int row = nb + rr;
            unsigned int tv = Ht32[rr * (HT_LD / 2) + lane];
            float cx = b2f((unsigned short)tv) + b2f((unsigned short)hv[it]);
            float cy = b2f((unsigned short)(tv >> 16)) + b2f((unsigned short)(hv[it] >> 16));
            float s = cx + cy, sq = cx * cx + cy * cy;
#pragma unroll
            for (int m = 32; m >= 1; m >>= 1) {
                s += __shfl_xor(s, m);
                sq += __shfl_xor(sq, m);
            }
            float mu = s * (1.f / 128.f);
            float var = sq * (1.f / 128.f) - mu * mu;
            float inv = rsqrtf(var + LNEPS);
            float z0 = fmaxf(fmaf((cx - mu) * inv, gg.x, cc.x), 0.f);
            float z1 = fmaxf(fmaf((cy - mu) * inv, gg.y, cc.y), 0.f);
            if (row < NN) {
                if (store_h) h32[(size_t)row * 64 + lane] = pack2(cx, cy);
                zb32[(size_t)row * 64 + lane] = pack2(z0, z1);
            }
        }
    }
}

// ---------------- atomic-free global mean pool (batch is sorted) ----------------
__global__ void k_gbounds(const int* __restrict__ batch, int* __restrict__ gstart) {
    int g = blockIdx.x * blockDim.x + threadIdx.x;
    if (g > NG) return;
    int lo = 0, hi = NN;
    while (lo < hi) {
        int mid = (lo + hi) >> 1;
        if (batch[mid] < g) lo = mid + 1;
        else hi = mid;
    }
    gstart[g] = lo;
}

__global__ void k_pool(const unsigned short* __restrict__ zb, const int* __restrict__ gstart,
                       float* __restrict__ out) {
    int g = blockIdx.x;
    int c = threadIdx.x;  // 128
    int a = gstart[g], b = gstart[g + 1];
    float s0 = 0.f, s1 = 0.f;
    int n = a;
    for (; n + 2 <= b; n += 2) {
        s0 += b2f(zb[(size_t)n * HD + c]);
        s1 += b2f(zb[(size_t)(n + 1) * HD + c]);
    }
    if (n < b) s0 += b2f(zb[(size_t)n * HD + c]);
    out[g * HD + c] = (s0 + s1) / fmaxf((float)(b - a), 1.f);
}

// ---------------- launch ----------------
extern "C" void kernel_launch(void* const* d_in, const int* in_sizes, int n_in, void* d_out,
                              int out_size, void* d_ws, size_t ws_size, hipStream_t stream) {
    const float* x     = (const float*)d_in[0];
    const int* ei      = (const int*)d_in[1];
    const float* eattr = (const float*)d_in[2];
    const int* batch   = (const int*)d_in[3];
    const float* encW  = (const float*)d_in[4];
    const float* encB  = (const float*)d_in[5];
    const float* eW    = (const float*)d_in[6];
    const float* eB    = (const float*)d_in[7];
    const float* ln_g  = (const float*)d_in[8];
    const float* ln_b  = (const float*)d_in[9];
    const float* W1    = (const float*)d_in[10];
    const float* b1    = (const float*)d_in[11];
    const float* mlg   = (const float*)d_in[12];
    const float* mlb   = (const float*)d_in[13];
    const float* W2    = (const float*)d_in[14];
    const float* b2    = (const float*)d_in[15];
    const float* t     = (const float*)d_in[16];
    const int* src = ei;
    const int* dst = ei + NE;

    char* w = (char*)d_ws;
    auto alloc = [&](size_t bytes) {
        char* p = w;
        w += (bytes + 255) & ~size_t(255);
        return p;
    };
    unsigned short* h    = (unsigned short*)alloc(sizeof(unsigned short) * NN * HD);
    unsigned short* zb   = (unsigned short*)alloc(sizeof(unsigned short) * NN * HD);
    unsigned int* outb   = (unsigned int*)alloc(sizeof(unsigned int) * NN * HD / 2);
    float4* aperm        = (float4*)alloc(sizeof(float4) * NE);
    int* row_start       = (int*)alloc(sizeof(int) * (NN + 1));
    int* counts          = (int*)alloc(sizeof(int) * NN);
    int* cursor          = (int*)alloc(sizeof(int) * NN);
    int* incl            = (int*)alloc(sizeof(int) * NN);
    int* bsum            = (int*)alloc(sizeof(int) * 128);
    int* boff            = (int*)alloc(sizeof(int) * 128);
    int* gstart          = (int*)alloc(sizeof(int) * (NG + 1));
    unsigned short* W1T  = (unsigned short*)alloc(sizeof(unsigned short) * NL * HD * HD2);
    unsigned short* W2T  = (unsigned short*)alloc(sizeof(unsigned short) * NL * HD2 * HD);

    hipMemsetAsync(counts, 0, sizeof(int) * NN, stream);
    hipMemsetAsync(cursor, 0, sizeof(int) * NN, stream);

    k_prep<<<512, 256, 0, stream>>>(W1, W2, W1T, W2T);
    k_encode_nodes<<<1024, 256, 0, stream>>>(x, encW, encB, zb);
    k_hist<<<(NE + 255) / 256, 256, 0, stream>>>(dst, counts);
    int nsb = (NN + SCAN_B - 1) / SCAN_B;
    k_scan1<<<nsb, SCAN_B, 0, stream>>>(counts, incl, bsum);
    k_scan2<<<1, 128, 0, stream>>>(bsum, boff, nsb);
    k_scan3<<<nsb, SCAN_B, 0, stream>>>(incl, boff, row_start);
    k_scatter<<<(NE + 255) / 256, 256, 0, stream>>>(src, dst, eattr, row_start, cursor, aperm);
    k_gbounds<<<(NG + 256) / 256, 256, 0, stream>>>(batch, gstart);

    for (int l = 0; l < NL; l++) {
        k_aggregate<<<(NN + 3) / 4, 256, 0, stream>>>(zb, aperm, row_start, eW, eB, t, l, outb);
        int ln_next = (l + 1) % NL;  // layer 3 fuses the final ln (reuses layer-0 params)
        k_mlp<<<(NN + BM - 1) / BM, 256, 0, stream>>>(
            (const unsigned short*)outb, W1T + (size_t)l * HD * HD2, b1 + l * HD2,
            mlg + l * HD2, mlb + l * HD2, W2T + (size_t)l * HD2 * HD, b2 + l * HD, h,
            ln_g + ln_next * HD, ln_b + ln_next * HD, zb, l > 0, l < NL - 1);
    }
    k_pool<<<NG, HD, 0, stream>>>(zb, gstart, (float*)d_out);
}

// Round 5
// 502.922 us; speedup vs baseline: 1.0637x; 1.0637x over previous
//
#include <hip/hip_runtime.h>

#define NN 50000
#define NE 500000
#define HD 128
#define HD2 256
#define NL 4
#define NG 1000

constexpr float MSG_EPS = 1e-7f;
constexpr float LNEPS   = 1e-5f;

typedef float  f32x4  __attribute__((ext_vector_type(4)));
typedef __bf16 bf16x8 __attribute__((ext_vector_type(8)));

__device__ __forceinline__ unsigned short f2b(float f) {
    unsigned int u = __float_as_uint(f);
    unsigned int r = u + 0x7FFFu + ((u >> 16) & 1u);
    return (unsigned short)(r >> 16);
}
__device__ __forceinline__ float b2f(unsigned short h) {
    return __uint_as_float(((unsigned int)h) << 16);
}
__device__ __forceinline__ unsigned int pack2(float a, float b) {
    return (unsigned int)f2b(a) | ((unsigned int)f2b(b) << 16);
}

// ---------------- node encoder: z0 = bf16(x @ Wn + bn) ----------------
__global__ void k_encode_nodes(const float* __restrict__ x, const float* __restrict__ W,
                               const float* __restrict__ b, unsigned short* __restrict__ zb) {
    int n = blockIdx.x;
    int c = threadIdx.x;  // 128
    float xr[9];
#pragma unroll
    for (int k = 0; k < 9; k++) xr[k] = x[n * 9 + k];
    float acc = b[c];
#pragma unroll
    for (int k = 0; k < 9; k++) acc = fmaf(xr[k], W[k * HD + c], acc);
    zb[n * HD + c] = f2b(acc);
}

// ---------------- weight prep: fp32 -> bf16 transposed ----------------
__global__ void k_prep(const float* __restrict__ W1, const float* __restrict__ W2,
                       unsigned short* __restrict__ W1T, unsigned short* __restrict__ W2T) {
    int idx = blockIdx.x * 256 + threadIdx.x;  // 131072 total
    {
        int k = idx & 127, n = (idx >> 7) & 255, l = idx >> 15;
        W1T[idx] = f2b(W1[(l * 128 + k) * 256 + n]);
    }
    {
        int k = idx & 255, n = (idx >> 8) & 127, l = idx >> 15;
        W2T[idx] = f2b(W2[(l * 256 + k) * 128 + n]);
    }
}

// ---------------- CSR build ----------------
__global__ void k_hist(const int* __restrict__ dst, int* __restrict__ counts) {
    int e = blockIdx.x * blockDim.x + threadIdx.x;
    if (e < NE) atomicAdd(&counts[dst[e]], 1);
}

#define SCAN_B 512
__global__ void k_scan1(const int* __restrict__ counts, int* __restrict__ incl,
                        int* __restrict__ bsum) {
    __shared__ int s[SCAN_B];
    int i = blockIdx.x * SCAN_B + threadIdx.x;
    int v = (i < NN) ? counts[i] : 0;
    s[threadIdx.x] = v;
    __syncthreads();
    for (int off = 1; off < SCAN_B; off <<= 1) {
        int t = (threadIdx.x >= off) ? s[threadIdx.x - off] : 0;
        __syncthreads();
        s[threadIdx.x] += t;
        __syncthreads();
    }
    if (i < NN) incl[i] = s[threadIdx.x];
    if (threadIdx.x == SCAN_B - 1) bsum[blockIdx.x] = s[threadIdx.x];
}

__global__ void k_scan2(const int* __restrict__ bsum, int* __restrict__ boff, int nb) {
    __shared__ int s[128];
    int v = (threadIdx.x < nb) ? bsum[threadIdx.x] : 0;
    s[threadIdx.x] = v;
    __syncthreads();
    for (int off = 1; off < 128; off <<= 1) {
        int t = (threadIdx.x >= off) ? s[threadIdx.x - off] : 0;
        __syncthreads();
        s[threadIdx.x] += t;
        __syncthreads();
    }
    if (threadIdx.x < nb) boff[threadIdx.x] = s[threadIdx.x] - v;  // exclusive
}

__global__ void k_scan3(const int* __restrict__ incl, const int* __restrict__ boff,
                        int* __restrict__ row_start) {
    int i = blockIdx.x * SCAN_B + threadIdx.x;
    if (i < NN) row_start[i + 1] = incl[i] + boff[blockIdx.x];
    if (i == 0) row_start[0] = 0;
}

// pack {attr0, attr1, attr2, src<<6} per CSR slot (src premultiplied: z-row offset
// in uints, so the gather address is a single 32-bit add per edge)
__global__ void k_scatter(const int* __restrict__ src, const int* __restrict__ dst,
                          const float* __restrict__ eattr, const int* __restrict__ row_start,
                          int* __restrict__ cursor, float4* __restrict__ aperm) {
    int e = blockIdx.x * blockDim.x + threadIdx.x;
    if (e >= NE) return;
    int d = dst[e];
    int p = row_start[d] + atomicAdd(&cursor[d], 1);
    float4 v;
    v.x = eattr[e * 3 + 0];
    v.y = eattr[e * 3 + 1];
    v.z = eattr[e * 3 + 2];
    v.w = __int_as_float(src[e] << 6);
    aperm[p] = v;
}

// ---------------- per-edge softmax-agg accumulate (2 channels/lane) ----------------
__device__ __forceinline__ void edge_acc2(float4 a, unsigned int zz, float2 w0, float2 w1,
                                          float2 w2, float2 bb, float tv, float& num0,
                                          float& num1, float& wm0, float& wm1) {
    float zx = b2f((unsigned short)zz), zy = b2f((unsigned short)(zz >> 16));
    float eax = fmaf(a.x, w0.x, fmaf(a.y, w1.x, fmaf(a.z, w2.x, bb.x)));
    float eay = fmaf(a.x, w0.y, fmaf(a.y, w1.y, fmaf(a.z, w2.y, bb.y)));
    float mx = fmaxf(zx + eax, 0.f) + MSG_EPS;
    float my = fmaxf(zy + eay, 0.f) + MSG_EPS;
    float ex = __expf(tv * mx), ey = __expf(tv * my);
    num0 += ex;
    num1 += ey;
    wm0 = fmaf(mx, ex, wm0);
    wm1 = fmaf(my, ey, wm1);
}

// ---------------- softmax aggregation: one wave per node, 2 channels/lane ----------
// Software-pipelined edge loop (verified round-3 version): while the current 4-edge
// group's z-gathers are in flight, the NEXT group's aperm rows load.
__global__ __launch_bounds__(256) void k_aggregate(const unsigned short* __restrict__ zbin,
                                                   const float4* __restrict__ aperm,
                                                   const int* __restrict__ row_start,
                                                   const float* __restrict__ We,
                                                   const float* __restrict__ be,
                                                   const float* __restrict__ t, int layer,
                                                   unsigned int* __restrict__ outb) {
    int w = threadIdx.x >> 6, lane = threadIdx.x & 63;
    int n = blockIdx.x * 4 + w;
    if (n >= NN) return;
    int c = lane * 2;
    float2 w0 = *(const float2*)&We[c];
    float2 w1 = *(const float2*)&We[HD + c];
    float2 w2 = *(const float2*)&We[2 * HD + c];
    float2 bb = *(const float2*)&be[c];
    float tv = t[layer];
    int s0 = row_start[n], s1 = row_start[n + 1];
    const unsigned int* z32 = (const unsigned int*)zbin;
    unsigned int zn = z32[(size_t)n * 64 + lane];  // self row, early issue
    float num0 = 0.f, num1 = 0.f, wm0 = 0.f, wm1 = 0.f;
    int p = s0;
    if (p + 4 <= s1) {
        float4 A0 = aperm[p], A1 = aperm[p + 1], A2 = aperm[p + 2], A3 = aperm[p + 3];
        for (; p + 8 <= s1; p += 4) {
            unsigned int g0 = z32[(unsigned int)__float_as_int(A0.w) + lane];
            unsigned int g1 = z32[(unsigned int)__float_as_int(A1.w) + lane];
            unsigned int g2 = z32[(unsigned int)__float_as_int(A2.w) + lane];
            unsigned int g3 = z32[(unsigned int)__float_as_int(A3.w) + lane];
            float4 B0 = aperm[p + 4], B1 = aperm[p + 5], B2 = aperm[p + 6],
                   B3 = aperm[p + 7];
            edge_acc2(A0, g0, w0, w1, w2, bb, tv, num0, num1, wm0, wm1);
            edge_acc2(A1, g1, w0, w1, w2, bb, tv, num0, num1, wm0, wm1);
            edge_acc2(A2, g2, w0, w1, w2, bb, tv, num0, num1, wm0, wm1);
            edge_acc2(A3, g3, w0, w1, w2, bb, tv, num0, num1, wm0, wm1);
            A0 = B0;
            A1 = B1;
            A2 = B2;
            A3 = B3;
        }
        {  // last full group (guaranteed: p+4 <= s1 < p+8)
            unsigned int g0 = z32[(unsigned int)__float_as_int(A0.w) + lane];
            unsigned int g1 = z32[(unsigned int)__float_as_int(A1.w) + lane];
            unsigned int g2 = z32[(unsigned int)__float_as_int(A2.w) + lane];
            unsigned int g3 = z32[(unsigned int)__float_as_int(A3.w) + lane];
            edge_acc2(A0, g0, w0, w1, w2, bb, tv, num0, num1, wm0, wm1);
            edge_acc2(A1, g1, w0, w1, w2, bb, tv, num0, num1, wm0, wm1);
            edge_acc2(A2, g2, w0, w1, w2, bb, tv, num0, num1, wm0, wm1);
            edge_acc2(A3, g3, w0, w1, w2, bb, tv, num0, num1, wm0, wm1);
            p += 4;
        }
    }
    for (; p < s1; p++) {
        float4 a = aperm[p];
        unsigned int zz = z32[(unsigned int)__float_as_int(a.w) + lane];
        edge_acc2(a, zz, w0, w1, w2, bb, tv, num0, num1, wm0, wm1);
    }
    float ox = ((s1 > s0) ? (wm0 / num0) : 0.f) + b2f((unsigned short)zn);
    float oy = ((s1 > s0) ? (wm1 / num1) : 0.f) + b2f((unsigned short)(zn >> 16));
    outb[(size_t)n * 64 + lane] = pack2(ox, oy);
}

// ---------------- fused MFMA MLP + next-layer LN+relu ----------------
// hnew = (add? h : 0) + relu(LN(A@W1+b1))@W2+b2 ; h=bf16(hnew); zb=bf16(relu(LN_next(hnew)))
// NEW: BM=64, 512 threads / 8 waves. Each block reads the 128 KB W1T/W2T stream ONCE
// for 64 rows (was 32) -> total weight L2 traffic halved (the measured k_mlp limiter).
// A tile staged coalesced into LDS (reuses the Ht buffer); GEMM1 cols split 8x32,
// GEMM2 cols 8x16; LN(256) exchange widened to 8 partials/row. Epilogue identical
// (residual h prefetched at entry, coalesced row-wise stores, in-wave LN(128)).
#define BM 64
#define HS_LD 264  // bf16 row stride (256+8)
#define AS_W 68    // As/Ht row stride in uints (272 B, 16B-aligned rows)

__global__ __launch_bounds__(512, 4) void k_mlp(const unsigned short* __restrict__ outb,
                                                const unsigned short* __restrict__ W1T,
                                                const float* __restrict__ b1l,
                                                const float* __restrict__ lgl,
                                                const float* __restrict__ lbl,
                                                const unsigned short* __restrict__ W2T,
                                                const float* __restrict__ b2l,
                                                unsigned short* __restrict__ h,
                                                const float* __restrict__ gn,
                                                const float* __restrict__ bn,
                                                unsigned short* __restrict__ zb,
                                                int add_residual, int store_h) {
    __shared__ __align__(16) unsigned short Hs[BM * HS_LD];  // 33792 B
    __shared__ __align__(16) unsigned int AsHt[BM * AS_W];   // 17408 B (As, then Ht)
    __shared__ __align__(16) float2 st1[4][16][8];           // 4096 B

    int nb = blockIdx.x * BM;
    int tid = threadIdx.x;
    int w = tid >> 6, lane = tid & 63, q = lane >> 4, i = lane & 15;

    // ---- epilogue prefetch: residual h rows + final-LN params ----
    unsigned int hv[8];
    const unsigned int* h32c = (const unsigned int*)h;
    if (add_residual) {
#pragma unroll
        for (int it = 0; it < 8; it++) {
            int row = nb + w + it * 8;
            hv[it] = (row < NN) ? h32c[(size_t)row * 64 + lane] : 0u;
        }
    } else {
#pragma unroll
        for (int it = 0; it < 8; it++) hv[it] = 0u;
    }
    float2 gg = *(const float2*)&gn[lane * 2];
    float2 cc = *(const float2*)&bn[lane * 2];

    // ---- stage A tile (64 rows x 128 ch bf16) coalesced into AsHt ----
    {
        const float4* src = (const float4*)outb;  // 16 float4 per row
        int r0 = tid >> 4, slot = tid & 15;
#pragma unroll
        for (int it = 0; it < 2; it++) {
            int r = r0 + it * 32;
            int row = nb + r;
            float4 v = (row < NN) ? src[(size_t)row * 16 + slot]
                                  : make_float4(0.f, 0.f, 0.f, 0.f);
            *(float4*)&AsHt[r * AS_W + slot * 4] = v;
        }
    }
    __syncthreads();

    // ---- GEMM1: 64x256, K=128; A from LDS, B from L2. wave w: cols w*32+ct*16+i ----
    f32x4 acc[4][2];
#pragma unroll
    for (int rt = 0; rt < 4; rt++)
#pragma unroll
        for (int ct = 0; ct < 2; ct++) acc[rt][ct] = (f32x4){0.f, 0.f, 0.f, 0.f};

#pragma unroll
    for (int ks = 0; ks < 4; ks++) {
        bf16x8 av[4], bv[2];
#pragma unroll
        for (int rt = 0; rt < 4; rt++)
            av[rt] = *(const bf16x8*)&AsHt[(rt * 16 + i) * AS_W + ks * 16 + q * 4];
#pragma unroll
        for (int ct = 0; ct < 2; ct++)
            bv[ct] = *(const bf16x8*)&W1T[(w * 32 + ct * 16 + i) * HD + ks * 32 + q * 8];
#pragma unroll
        for (int rt = 0; rt < 4; rt++)
#pragma unroll
            for (int ct = 0; ct < 2; ct++)
                acc[rt][ct] = __builtin_amdgcn_mfma_f32_16x16x32_bf16(av[rt], bv[ct],
                                                                     acc[rt][ct], 0, 0, 0);
    }

    // ---- +b1 ----
#pragma unroll
    for (int ct = 0; ct < 2; ct++) {
        float bb = b1l[w * 32 + ct * 16 + i];
#pragma unroll
        for (int rt = 0; rt < 4; rt++)
#pragma unroll
            for (int r = 0; r < 4; r++) acc[rt][ct][r] += bb;
    }

    // ---- LN(256) stats in-register + 8-wave exchange ----
    {
        float sv[4][4], qv[4][4];
#pragma unroll
        for (int rt = 0; rt < 4; rt++)
#pragma unroll
            for (int r = 0; r < 4; r++) {
                float s = acc[rt][0][r] + acc[rt][1][r];
                float sq = fmaf(acc[rt][0][r], acc[rt][0][r],
                                acc[rt][1][r] * acc[rt][1][r]);
                sv[rt][r] = s;
                qv[rt][r] = sq;
            }
#pragma unroll
        for (int m = 1; m <= 8; m <<= 1)
#pragma unroll
            for (int rt = 0; rt < 4; rt++)
#pragma unroll
                for (int r = 0; r < 4; r++) {
                    sv[rt][r] += __shfl_xor(sv[rt][r], m);
                    qv[rt][r] += __shfl_xor(qv[rt][r], m);
                }
        if (i == 0) {
#pragma unroll
            for (int rt = 0; rt < 4; rt++)
#pragma unroll
                for (int r = 0; r < 4; r++)
                    st1[rt][q * 4 + r][w] = make_float2(sv[rt][r], qv[rt][r]);
        }
    }
    __syncthreads();

    {
        float mu[4][4], inv[4][4];
#pragma unroll
        for (int rt = 0; rt < 4; rt++)
#pragma unroll
            for (int r = 0; r < 4; r++) {
                const float4* sp = (const float4*)&st1[rt][q * 4 + r][0];
                float4 a = sp[0], b = sp[1], c4 = sp[2], d4 = sp[3];
                float S = a.x + a.z + b.x + b.z + c4.x + c4.z + d4.x + d4.z;
                float Q = a.y + a.w + b.y + b.w + c4.y + c4.w + d4.y + d4.w;
                float m_ = S * (1.f / 256.f);
                float v_ = Q * (1.f / 256.f) - m_ * m_;
                mu[rt][r] = m_;
                inv[rt][r] = rsqrtf(v_ + LNEPS);
            }
#pragma unroll
        for (int ct = 0; ct < 2; ct++) {
            float g = lgl[w * 32 + ct * 16 + i];
            float c = lbl[w * 32 + ct * 16 + i];
#pragma unroll
            for (int rt = 0; rt < 4; rt++)
#pragma unroll
                for (int r = 0; r < 4; r++) {
                    float v =
                        fmaxf(fmaf((acc[rt][ct][r] - mu[rt][r]) * inv[rt][r], g, c), 0.f);
                    Hs[(rt * 16 + q * 4 + r) * HS_LD + w * 32 + ct * 16 + i] = f2b(v);
                }
        }
    }
    __syncthreads();

    // ---- GEMM2: 64x128, K=256; A from Hs; wave w: cols w*16+i ----
    f32x4 acc2[4];
#pragma unroll
    for (int rt = 0; rt < 4; rt++) acc2[rt] = (f32x4){0.f, 0.f, 0.f, 0.f};

#pragma unroll
    for (int ks = 0; ks < 8; ks++) {
        bf16x8 hc[4];
#pragma unroll
        for (int rt = 0; rt < 4; rt++)
            hc[rt] = *(const bf16x8*)&Hs[(rt * 16 + i) * HS_LD + ks * 32 + q * 8];
        bf16x8 bc = *(const bf16x8*)&W2T[(w * 16 + i) * HD2 + ks * 32 + q * 8];
#pragma unroll
        for (int rt = 0; rt < 4; rt++)
            acc2[rt] = __builtin_amdgcn_mfma_f32_16x16x32_bf16(hc[rt], bc, acc2[rt], 0, 0, 0);
    }

    // ---- conv-out (+b2) -> bf16 LDS tile Ht (reuses As memory; As is dead) ----
    {
        unsigned short* Ht = (unsigned short*)AsHt;  // stride 2*AS_W shorts = 136
        float bb = b2l[w * 16 + i];
#pragma unroll
        for (int rt = 0; rt < 4; rt++)
#pragma unroll
            for (int r = 0; r < 4; r++)
                Ht[(rt * 16 + q * 4 + r) * (2 * AS_W) + w * 16 + i] = f2b(acc2[rt][r] + bb);
    }
    __syncthreads();

    // ---- row-wise COALESCED epilogue: residual (pre-fetched), h store, LN(128), zb ----
    {
        const unsigned int* Ht32 = AsHt;
        unsigned int* h32 = (unsigned int*)h;
        unsigned int* zb32 = (unsigned int*)zb;
#pragma unroll
        for (int it = 0; it < 8; it++) {
            int rr = w + it * 8;
            int row = nb + rr;
            unsigned int tv = Ht32[rr * AS_W + lane];
            float cx = b2f((unsigned short)tv) + b2f((unsigned short)hv[it]);
            float cy = b2f((unsigned short)(tv >> 16)) + b2f((unsigned short)(hv[it] >> 16));
            float s = cx + cy, sq = cx * cx + cy * cy;
#pragma unroll
            for (int m = 32; m >= 1; m >>= 1) {
                s += __shfl_xor(s, m);
                sq += __shfl_xor(sq, m);
            }
            float mu = s * (1.f / 128.f);
            float var = sq * (1.f / 128.f) - mu * mu;
            float inv = rsqrtf(var + LNEPS);
            float z0 = fmaxf(fmaf((cx - mu) * inv, gg.x, cc.x), 0.f);
            float z1 = fmaxf(fmaf((cy - mu) * inv, gg.y, cc.y), 0.f);
            if (row < NN) {
                if (store_h) h32[(size_t)row * 64 + lane] = pack2(cx, cy);
                zb32[(size_t)row * 64 + lane] = pack2(z0, z1);
            }
        }
    }
}

// ---------------- atomic-free global mean pool (batch is sorted) ----------------
__global__ void k_gbounds(const int* __restrict__ batch, int* __restrict__ gstart) {
    int g = blockIdx.x * blockDim.x + threadIdx.x;
    if (g > NG) return;
    int lo = 0, hi = NN;
    while (lo < hi) {
        int mid = (lo + hi) >> 1;
        if (batch[mid] < g) lo = mid + 1;
        else hi = mid;
    }
    gstart[g] = lo;
}

__global__ void k_pool(const unsigned short* __restrict__ zb, const int* __restrict__ gstart,
                       float* __restrict__ out) {
    int g = blockIdx.x;
    int c = threadIdx.x;  // 128
    int a = gstart[g], b = gstart[g + 1];
    float s0 = 0.f, s1 = 0.f;
    int n = a;
    for (; n + 2 <= b; n += 2) {
        s0 += b2f(zb[(size_t)n * HD + c]);
        s1 += b2f(zb[(size_t)(n + 1) * HD + c]);
    }
    if (n < b) s0 += b2f(zb[(size_t)n * HD + c]);
    out[g * HD + c] = (s0 + s1) / fmaxf((float)(b - a), 1.f);
}

// ---------------- launch ----------------
extern "C" void kernel_launch(void* const* d_in, const int* in_sizes, int n_in, void* d_out,
                              int out_size, void* d_ws, size_t ws_size, hipStream_t stream) {
    const float* x     = (const float*)d_in[0];
    const int* ei      = (const int*)d_in[1];
    const float* eattr = (const float*)d_in[2];
    const int* batch   = (const int*)d_in[3];
    const float* encW  = (const float*)d_in[4];
    const float* encB  = (const float*)d_in[5];
    const float* eW    = (const float*)d_in[6];
    const float* eB    = (const float*)d_in[7];
    const float* ln_g  = (const float*)d_in[8];
    const float* ln_b  = (const float*)d_in[9];
    const float* W1    = (const float*)d_in[10];
    const float* b1    = (const float*)d_in[11];
    const float* mlg   = (const float*)d_in[12];
    const float* mlb   = (const float*)d_in[13];
    const float* W2    = (const float*)d_in[14];
    const float* b2    = (const float*)d_in[15];
    const float* t     = (const float*)d_in[16];
    const int* src = ei;
    const int* dst = ei + NE;

    char* w = (char*)d_ws;
    auto alloc = [&](size_t bytes) {
        char* p = w;
        w += (bytes + 255) & ~size_t(255);
        return p;
    };
    unsigned short* h    = (unsigned short*)alloc(sizeof(unsigned short) * NN * HD);
    unsigned short* zb   = (unsigned short*)alloc(sizeof(unsigned short) * NN * HD);
    unsigned int* outb   = (unsigned int*)alloc(sizeof(unsigned int) * NN * HD / 2);
    float4* aperm        = (float4*)alloc(sizeof(float4) * NE);
    int* row_start       = (int*)alloc(sizeof(int) * (NN + 1));
    int* counts          = (int*)alloc(sizeof(int) * NN);
    int* cursor          = (int*)alloc(sizeof(int) * NN);
    int* incl            = (int*)alloc(sizeof(int) * NN);
    int* bsum            = (int*)alloc(sizeof(int) * 128);
    int* boff            = (int*)alloc(sizeof(int) * 128);
    int* gstart          = (int*)alloc(sizeof(int) * (NG + 1));
    unsigned short* W1T  = (unsigned short*)alloc(sizeof(unsigned short) * NL * HD * HD2);
    unsigned short* W2T  = (unsigned short*)alloc(sizeof(unsigned short) * NL * HD2 * HD);

    hipMemsetAsync(counts, 0, sizeof(int) * NN, stream);
    hipMemsetAsync(cursor, 0, sizeof(int) * NN, stream);

    k_prep<<<512, 256, 0, stream>>>(W1, W2, W1T, W2T);
    k_encode_nodes<<<NN, HD, 0, stream>>>(x, encW, encB, zb);
    k_hist<<<(NE + 255) / 256, 256, 0, stream>>>(dst, counts);
    int nsb = (NN + SCAN_B - 1) / SCAN_B;
    k_scan1<<<nsb, SCAN_B, 0, stream>>>(counts, incl, bsum);
    k_scan2<<<1, 128, 0, stream>>>(bsum, boff, nsb);
    k_scan3<<<nsb, SCAN_B, 0, stream>>>(incl, boff, row_start);
    k_scatter<<<(NE + 255) / 256, 256, 0, stream>>>(src, dst, eattr, row_start, cursor, aperm);
    k_gbounds<<<(NG + 256) / 256, 256, 0, stream>>>(batch, gstart);

    for (int l = 0; l < NL; l++) {
        k_aggregate<<<(NN + 3) / 4, 256, 0, stream>>>(zb, aperm, row_start, eW, eB, t, l, outb);
        int ln_next = (l + 1) % NL;  // layer 3 fuses the final ln (reuses layer-0 params)
        k_mlp<<<(NN + BM - 1) / BM, 512, 0, stream>>>(
            (const unsigned short*)outb, W1T + (size_t)l * HD * HD2, b1 + l * HD2,
            mlg + l * HD2, mlb + l * HD2, W2T + (size_t)l * HD2 * HD, b2 + l * HD, h,
            ln_g + ln_next * HD, ln_b + ln_next * HD, zb, l > 0, l < NL - 1);
    }
    k_pool<<<NG, HD, 0, stream>>>(zb, gstart, (float*)d_out);
}

// Round 6
// 501.753 us; speedup vs baseline: 1.0662x; 1.0023x over previous
//
#include <hip/hip_runtime.h>

#define NN 50000
#define NE 500000
#define HD 128
#define HD2 256
#define NL 4
#define NG 1000

constexpr float MSG_EPS = 1e-7f;
constexpr float LNEPS   = 1e-5f;

typedef float  f32x4  __attribute__((ext_vector_type(4)));
typedef __bf16 bf16x8 __attribute__((ext_vector_type(8)));

__device__ __forceinline__ unsigned short f2b(float f) {
    unsigned int u = __float_as_uint(f);
    unsigned int r = u + 0x7FFFu + ((u >> 16) & 1u);
    return (unsigned short)(r >> 16);
}
__device__ __forceinline__ float b2f(unsigned short h) {
    return __uint_as_float(((unsigned int)h) << 16);
}
__device__ __forceinline__ unsigned int pack2(float a, float b) {
    return (unsigned int)f2b(a) | ((unsigned int)f2b(b) << 16);
}

// ---------------- node encoder: z0 = bf16(x @ Wn + bn) ----------------
__global__ void k_encode_nodes(const float* __restrict__ x, const float* __restrict__ W,
                               const float* __restrict__ b, unsigned short* __restrict__ zb) {
    int n = blockIdx.x;
    int c = threadIdx.x;  // 128
    float xr[9];
#pragma unroll
    for (int k = 0; k < 9; k++) xr[k] = x[n * 9 + k];
    float acc = b[c];
#pragma unroll
    for (int k = 0; k < 9; k++) acc = fmaf(xr[k], W[k * HD + c], acc);
    zb[n * HD + c] = f2b(acc);
}

// ---------------- weight prep: fp32 -> bf16 transposed ----------------
__global__ void k_prep(const float* __restrict__ W1, const float* __restrict__ W2,
                       unsigned short* __restrict__ W1T, unsigned short* __restrict__ W2T) {
    int idx = blockIdx.x * 256 + threadIdx.x;  // 131072 total
    {
        int k = idx & 127, n = (idx >> 7) & 255, l = idx >> 15;
        W1T[idx] = f2b(W1[(l * 128 + k) * 256 + n]);
    }
    {
        int k = idx & 255, n = (idx >> 8) & 127, l = idx >> 15;
        W2T[idx] = f2b(W2[(l * 256 + k) * 128 + n]);
    }
}

// ---------------- CSR build ----------------
__global__ void k_hist(const int* __restrict__ dst, int* __restrict__ counts) {
    int e = blockIdx.x * blockDim.x + threadIdx.x;
    if (e < NE) atomicAdd(&counts[dst[e]], 1);
}

#define SCAN_B 512
__global__ void k_scan1(const int* __restrict__ counts, int* __restrict__ incl,
                        int* __restrict__ bsum) {
    __shared__ int s[SCAN_B];
    int i = blockIdx.x * SCAN_B + threadIdx.x;
    int v = (i < NN) ? counts[i] : 0;
    s[threadIdx.x] = v;
    __syncthreads();
    for (int off = 1; off < SCAN_B; off <<= 1) {
        int t = (threadIdx.x >= off) ? s[threadIdx.x - off] : 0;
        __syncthreads();
        s[threadIdx.x] += t;
        __syncthreads();
    }
    if (i < NN) incl[i] = s[threadIdx.x];
    if (threadIdx.x == SCAN_B - 1) bsum[blockIdx.x] = s[threadIdx.x];
}

__global__ void k_scan2(const int* __restrict__ bsum, int* __restrict__ boff, int nb) {
    __shared__ int s[128];
    int v = (threadIdx.x < nb) ? bsum[threadIdx.x] : 0;
    s[threadIdx.x] = v;
    __syncthreads();
    for (int off = 1; off < 128; off <<= 1) {
        int t = (threadIdx.x >= off) ? s[threadIdx.x - off] : 0;
        __syncthreads();
        s[threadIdx.x] += t;
        __syncthreads();
    }
    if (threadIdx.x < nb) boff[threadIdx.x] = s[threadIdx.x] - v;  // exclusive
}

__global__ void k_scan3(const int* __restrict__ incl, const int* __restrict__ boff,
                        int* __restrict__ row_start) {
    int i = blockIdx.x * SCAN_B + threadIdx.x;
    if (i < NN) row_start[i + 1] = incl[i] + boff[blockIdx.x];
    if (i == 0) row_start[0] = 0;
}

// pack {attr0, attr1, attr2, src<<6} per CSR slot (src premultiplied: z-row offset
// in uints, so the gather address is a single 32-bit add per edge)
__global__ void k_scatter(const int* __restrict__ src, const int* __restrict__ dst,
                          const float* __restrict__ eattr, const int* __restrict__ row_start,
                          int* __restrict__ cursor, float4* __restrict__ aperm) {
    int e = blockIdx.x * blockDim.x + threadIdx.x;
    if (e >= NE) return;
    int d = dst[e];
    int p = row_start[d] + atomicAdd(&cursor[d], 1);
    float4 v;
    v.x = eattr[e * 3 + 0];
    v.y = eattr[e * 3 + 1];
    v.z = eattr[e * 3 + 2];
    v.w = __int_as_float(src[e] << 6);
    aperm[p] = v;
}

// ---------------- per-edge softmax-agg accumulate (2 channels/lane) ----------------
__device__ __forceinline__ void edge_acc2(float4 a, unsigned int zz, float2 w0, float2 w1,
                                          float2 w2, float2 bb, float tv, float& num0,
                                          float& num1, float& wm0, float& wm1) {
    float zx = b2f((unsigned short)zz), zy = b2f((unsigned short)(zz >> 16));
    float eax = fmaf(a.x, w0.x, fmaf(a.y, w1.x, fmaf(a.z, w2.x, bb.x)));
    float eay = fmaf(a.x, w0.y, fmaf(a.y, w1.y, fmaf(a.z, w2.y, bb.y)));
    float mx = fmaxf(zx + eax, 0.f) + MSG_EPS;
    float my = fmaxf(zy + eay, 0.f) + MSG_EPS;
    float ex = __expf(tv * mx), ey = __expf(tv * my);
    num0 += ex;
    num1 += ey;
    wm0 = fmaf(mx, ex, wm0);
    wm1 = fmaf(my, ey, wm1);
}

// ---------------- softmax aggregation: one wave per node, 2 channels/lane ----------
// Software-pipelined edge loop (verified round-3 version): while the current 4-edge
// group's z-gathers are in flight, the NEXT group's aperm rows load.
__global__ __launch_bounds__(256) void k_aggregate(const unsigned short* __restrict__ zbin,
                                                   const float4* __restrict__ aperm,
                                                   const int* __restrict__ row_start,
                                                   const float* __restrict__ We,
                                                   const float* __restrict__ be,
                                                   const float* __restrict__ t, int layer,
                                                   unsigned int* __restrict__ outb) {
    int w = threadIdx.x >> 6, lane = threadIdx.x & 63;
    int n = blockIdx.x * 4 + w;
    if (n >= NN) return;
    int c = lane * 2;
    float2 w0 = *(const float2*)&We[c];
    float2 w1 = *(const float2*)&We[HD + c];
    float2 w2 = *(const float2*)&We[2 * HD + c];
    float2 bb = *(const float2*)&be[c];
    float tv = t[layer];
    int s0 = row_start[n], s1 = row_start[n + 1];
    const unsigned int* z32 = (const unsigned int*)zbin;
    unsigned int zn = z32[(size_t)n * 64 + lane];  // self row, early issue
    float num0 = 0.f, num1 = 0.f, wm0 = 0.f, wm1 = 0.f;
    int p = s0;
    if (p + 4 <= s1) {
        float4 A0 = aperm[p], A1 = aperm[p + 1], A2 = aperm[p + 2], A3 = aperm[p + 3];
        for (; p + 8 <= s1; p += 4) {
            unsigned int g0 = z32[(unsigned int)__float_as_int(A0.w) + lane];
            unsigned int g1 = z32[(unsigned int)__float_as_int(A1.w) + lane];
            unsigned int g2 = z32[(unsigned int)__float_as_int(A2.w) + lane];
            unsigned int g3 = z32[(unsigned int)__float_as_int(A3.w) + lane];
            float4 B0 = aperm[p + 4], B1 = aperm[p + 5], B2 = aperm[p + 6],
                   B3 = aperm[p + 7];
            edge_acc2(A0, g0, w0, w1, w2, bb, tv, num0, num1, wm0, wm1);
            edge_acc2(A1, g1, w0, w1, w2, bb, tv, num0, num1, wm0, wm1);
            edge_acc2(A2, g2, w0, w1, w2, bb, tv, num0, num1, wm0, wm1);
            edge_acc2(A3, g3, w0, w1, w2, bb, tv, num0, num1, wm0, wm1);
            A0 = B0;
            A1 = B1;
            A2 = B2;
            A3 = B3;
        }
        {  // last full group (guaranteed: p+4 <= s1 < p+8)
            unsigned int g0 = z32[(unsigned int)__float_as_int(A0.w) + lane];
            unsigned int g1 = z32[(unsigned int)__float_as_int(A1.w) + lane];
            unsigned int g2 = z32[(unsigned int)__float_as_int(A2.w) + lane];
            unsigned int g3 = z32[(unsigned int)__float_as_int(A3.w) + lane];
            edge_acc2(A0, g0, w0, w1, w2, bb, tv, num0, num1, wm0, wm1);
            edge_acc2(A1, g1, w0, w1, w2, bb, tv, num0, num1, wm0, wm1);
            edge_acc2(A2, g2, w0, w1, w2, bb, tv, num0, num1, wm0, wm1);
            edge_acc2(A3, g3, w0, w1, w2, bb, tv, num0, num1, wm0, wm1);
            p += 4;
        }
    }
    for (; p < s1; p++) {
        float4 a = aperm[p];
        unsigned int zz = z32[(unsigned int)__float_as_int(a.w) + lane];
        edge_acc2(a, zz, w0, w1, w2, bb, tv, num0, num1, wm0, wm1);
    }
    float ox = ((s1 > s0) ? (wm0 / num0) : 0.f) + b2f((unsigned short)zn);
    float oy = ((s1 > s0) ? (wm1 / num1) : 0.f) + b2f((unsigned short)(zn >> 16));
    outb[(size_t)n * 64 + lane] = pack2(ox, oy);
}

// ---------------- fused MFMA MLP + next-layer LN+relu (round-3 verified core) -------
// hnew = (add? h : 0) + relu(LN(A@W1+b1))@W2+b2 ; h=bf16(hnew); zb=bf16(relu(LN_next(hnew)))
// BM=32, 4 waves. Full A tile + residual h rows + epilogue LN params prefetched at entry.
// NEW (pool_mode, last layer only): instead of storing zb (only consumer was k_pool),
// run-accumulate z over same-graph rows (batch is sorted -> 1-3 graph transitions per
// wave) and flush 2 fp32 atomics per (wave, graph) into gsum. Kills the 12.8 MB zb
// write + 12.8 MB pool re-read.
#define BM 32
#define HS_LD 264  // bf16 row stride (256+8)
#define HT_LD 136  // bf16 row stride (128+8); as uint: 68

__global__ __launch_bounds__(256) void k_mlp(const unsigned short* __restrict__ outb,
                                             const unsigned short* __restrict__ W1T,
                                             const float* __restrict__ b1l,
                                             const float* __restrict__ lgl,
                                             const float* __restrict__ lbl,
                                             const unsigned short* __restrict__ W2T,
                                             const float* __restrict__ b2l,
                                             unsigned short* __restrict__ h,
                                             const float* __restrict__ gn,
                                             const float* __restrict__ bn,
                                             unsigned short* __restrict__ zb,
                                             const int* __restrict__ batch,
                                             float* __restrict__ gsum,
                                             int add_residual, int store_h, int pool_mode) {
    __shared__ __align__(16) unsigned short Hs[BM * HS_LD];  // 16896 B
    __shared__ __align__(16) unsigned short Ht[BM * HT_LD];  // 8704 B
    __shared__ __align__(16) float2 st1[2][16][4];           // 1024 B

    int nb = blockIdx.x * BM;
    int tid = threadIdx.x;
    int w = tid >> 6, lane = tid & 63, q = lane >> 4, i = lane & 15;

    // ---- full A prefetch: all 8 fragments issue NOW (32 VGPR) ----
    bf16x8 areg[2][4];
#pragma unroll
    for (int rt = 0; rt < 2; rt++) {
        int row = nb + rt * 16 + i;
#pragma unroll
        for (int ks = 0; ks < 4; ks++)
            areg[rt][ks] = (row < NN)
                               ? *(const bf16x8*)&outb[(size_t)row * HD + ks * 32 + q * 8]
                               : (bf16x8)(__bf16)0.f;
    }

    // ---- epilogue prefetch: residual h rows + final-LN params ----
    unsigned int hv[8];
    const unsigned int* h32c = (const unsigned int*)h;
    if (add_residual) {
#pragma unroll
        for (int it = 0; it < 8; it++) {
            int row = nb + w + it * 4;
            hv[it] = (row < NN) ? h32c[(size_t)row * 64 + lane] : 0u;
        }
    } else {
#pragma unroll
        for (int it = 0; it < 8; it++) hv[it] = 0u;
    }
    float2 gg = *(const float2*)&gn[lane * 2];
    float2 cc = *(const float2*)&bn[lane * 2];

    // ---- GEMM1: 32x256, K=128; A in registers, B 1-step lookahead ----
    f32x4 acc[2][4];
#pragma unroll
    for (int rt = 0; rt < 2; rt++)
#pragma unroll
        for (int ct = 0; ct < 4; ct++) acc[rt][ct] = (f32x4){0.f, 0.f, 0.f, 0.f};

    bf16x8 bcur[4];
#pragma unroll
    for (int ct = 0; ct < 4; ct++)
        bcur[ct] = *(const bf16x8*)&W1T[(w * 64 + ct * 16 + i) * HD + q * 8];

#pragma unroll
    for (int ks = 0; ks < 4; ks++) {
        bf16x8 bnxt[4];
        if (ks < 3) {
#pragma unroll
            for (int ct = 0; ct < 4; ct++)
                bnxt[ct] =
                    *(const bf16x8*)&W1T[(w * 64 + ct * 16 + i) * HD + (ks + 1) * 32 + q * 8];
        }
#pragma unroll
        for (int rt = 0; rt < 2; rt++)
#pragma unroll
            for (int ct = 0; ct < 4; ct++)
                acc[rt][ct] = __builtin_amdgcn_mfma_f32_16x16x32_bf16(areg[rt][ks], bcur[ct],
                                                                     acc[rt][ct], 0, 0, 0);
        if (ks < 3) {
#pragma unroll
            for (int ct = 0; ct < 4; ct++) bcur[ct] = bnxt[ct];
        }
    }

    // ---- +b1 ----
#pragma unroll
    for (int ct = 0; ct < 4; ct++) {
        float bb = b1l[w * 64 + ct * 16 + i];
#pragma unroll
        for (int rt = 0; rt < 2; rt++)
#pragma unroll
            for (int r = 0; r < 4; r++) acc[rt][ct][r] += bb;
    }

    // ---- LN(256) stats in-register + cross-wave exchange ----
    {
        float sv[2][4], qv[2][4];
#pragma unroll
        for (int rt = 0; rt < 2; rt++)
#pragma unroll
            for (int r = 0; r < 4; r++) {
                float s = acc[rt][0][r] + acc[rt][1][r] + acc[rt][2][r] + acc[rt][3][r];
                float sq = 0.f;
#pragma unroll
                for (int ct = 0; ct < 4; ct++) sq = fmaf(acc[rt][ct][r], acc[rt][ct][r], sq);
                sv[rt][r] = s;
                qv[rt][r] = sq;
            }
#pragma unroll
        for (int m = 1; m <= 8; m <<= 1)
#pragma unroll
            for (int rt = 0; rt < 2; rt++)
#pragma unroll
                for (int r = 0; r < 4; r++) {
                    sv[rt][r] += __shfl_xor(sv[rt][r], m);
                    qv[rt][r] += __shfl_xor(qv[rt][r], m);
                }
        if (i == 0) {
#pragma unroll
            for (int rt = 0; rt < 2; rt++)
#pragma unroll
                for (int r = 0; r < 4; r++)
                    st1[rt][q * 4 + r][w] = make_float2(sv[rt][r], qv[rt][r]);
        }
    }
    __syncthreads();

    {
        float mu[2][4], inv[2][4];
#pragma unroll
        for (int rt = 0; rt < 2; rt++)
#pragma unroll
            for (int r = 0; r < 4; r++) {
                const float4* sp = (const float4*)&st1[rt][q * 4 + r][0];
                float4 a = sp[0], b = sp[1];
                float S = a.x + a.z + b.x + b.z;
                float Q = a.y + a.w + b.y + b.w;
                float m_ = S * (1.f / 256.f);
                float v_ = Q * (1.f / 256.f) - m_ * m_;
                mu[rt][r] = m_;
                inv[rt][r] = rsqrtf(v_ + LNEPS);
            }
#pragma unroll
        for (int ct = 0; ct < 4; ct++) {
            float g = lgl[w * 64 + ct * 16 + i];
            float c = lbl[w * 64 + ct * 16 + i];
#pragma unroll
            for (int rt = 0; rt < 2; rt++)
#pragma unroll
                for (int r = 0; r < 4; r++) {
                    float v =
                        fmaxf(fmaf((acc[rt][ct][r] - mu[rt][r]) * inv[rt][r], g, c), 0.f);
                    Hs[(rt * 16 + q * 4 + r) * HS_LD + w * 64 + ct * 16 + i] = f2b(v);
                }
        }
    }
    __syncthreads();

    // ---- GEMM2: 32x128, K=256; A from Hs, 1-step lookahead ----
    f32x4 acc2[2][2];
#pragma unroll
    for (int rt = 0; rt < 2; rt++)
#pragma unroll
        for (int ct = 0; ct < 2; ct++) acc2[rt][ct] = (f32x4){0.f, 0.f, 0.f, 0.f};

    bf16x8 hc[2], bc[2];
#pragma unroll
    for (int rt = 0; rt < 2; rt++) hc[rt] = *(const bf16x8*)&Hs[(rt * 16 + i) * HS_LD + q * 8];
#pragma unroll
    for (int ct = 0; ct < 2; ct++)
        bc[ct] = *(const bf16x8*)&W2T[(w * 32 + ct * 16 + i) * HD2 + q * 8];

#pragma unroll
    for (int ks = 0; ks < 8; ks++) {
        bf16x8 hn[2], bn2[2];
        if (ks < 7) {
#pragma unroll
            for (int rt = 0; rt < 2; rt++)
                hn[rt] = *(const bf16x8*)&Hs[(rt * 16 + i) * HS_LD + (ks + 1) * 32 + q * 8];
#pragma unroll
            for (int ct = 0; ct < 2; ct++)
                bn2[ct] =
                    *(const bf16x8*)&W2T[(w * 32 + ct * 16 + i) * HD2 + (ks + 1) * 32 + q * 8];
        }
#pragma unroll
        for (int rt = 0; rt < 2; rt++)
#pragma unroll
            for (int ct = 0; ct < 2; ct++)
                acc2[rt][ct] = __builtin_amdgcn_mfma_f32_16x16x32_bf16(hc[rt], bc[ct],
                                                                      acc2[rt][ct], 0, 0, 0);
        if (ks < 7) {
#pragma unroll
            for (int rt = 0; rt < 2; rt++) hc[rt] = hn[rt];
#pragma unroll
            for (int ct = 0; ct < 2; ct++) bc[ct] = bn2[ct];
        }
    }

    // ---- conv-out (+b2) -> bf16 LDS tile Ht (C-layout scatter; LDS absorbs it) ----
#pragma unroll
    for (int ct = 0; ct < 2; ct++) {
        float bb = b2l[w * 32 + ct * 16 + i];
#pragma unroll
        for (int rt = 0; rt < 2; rt++)
#pragma unroll
            for (int r = 0; r < 4; r++)
                Ht[(rt * 16 + q * 4 + r) * HT_LD + w * 32 + ct * 16 + i] =
                    f2b(acc2[rt][ct][r] + bb);
    }
    __syncthreads();

    // ---- row-wise COALESCED epilogue: residual (pre-fetched), h store, LN(128),
    //      then zb store OR per-graph pool accumulation ----
    {
        const unsigned int* Ht32 = (const unsigned int*)Ht;
        unsigned int* h32 = (unsigned int*)h;
        unsigned int* zb32 = (unsigned int*)zb;
        int gc = -1;
        float a0 = 0.f, a1 = 0.f;
#pragma unroll
        for (int it = 0; it < 8; it++) {
            int rr = w + it * 4;
            int row = nb + rr;
            unsigned int tv = Ht32[rr * (HT_LD / 2) + lane];
            float cx = b2f((unsigned short)tv) + b2f((unsigned short)hv[it]);
            float cy = b2f((unsigned short)(tv >> 16)) + b2f((unsigned short)(hv[it] >> 16));
            float s = cx + cy, sq = cx * cx + cy * cy;
#pragma unroll
            for (int m = 32; m >= 1; m >>= 1) {
                s += __shfl_xor(s, m);
                sq += __shfl_xor(sq, m);
            }
            float mu = s * (1.f / 128.f);
            float var = sq * (1.f / 128.f) - mu * mu;
            float inv = rsqrtf(var + LNEPS);
            float z0 = fmaxf(fmaf((cx - mu) * inv, gg.x, cc.x), 0.f);
            float z1 = fmaxf(fmaf((cy - mu) * inv, gg.y, cc.y), 0.f);
            if (row < NN) {
                if (store_h) h32[(size_t)row * 64 + lane] = pack2(cx, cy);
                if (!pool_mode) {
                    zb32[(size_t)row * 64 + lane] = pack2(z0, z1);
                } else {
                    int g = batch[row];  // wave-uniform (row depends on w, it only)
                    if (g != gc) {
                        if (gc >= 0) {
                            atomicAdd(&gsum[gc * HD + lane * 2], a0);
                            atomicAdd(&gsum[gc * HD + lane * 2 + 1], a1);
                        }
                        gc = g;
                        a0 = 0.f;
                        a1 = 0.f;
                    }
                    a0 += z0;
                    a1 += z1;
                }
            }
        }
        if (pool_mode && gc >= 0) {
            atomicAdd(&gsum[gc * HD + lane * 2], a0);
            atomicAdd(&gsum[gc * HD + lane * 2 + 1], a1);
        }
    }
}

// ---------------- graph bounds (batch is sorted) ----------------
__global__ void k_gbounds(const int* __restrict__ batch, int* __restrict__ gstart) {
    int g = blockIdx.x * blockDim.x + threadIdx.x;
    if (g > NG) return;
    int lo = 0, hi = NN;
    while (lo < hi) {
        int mid = (lo + hi) >> 1;
        if (batch[mid] < g) lo = mid + 1;
        else hi = mid;
    }
    gstart[g] = lo;
}

// ---------------- final divide: out = gsum / count ----------------
__global__ void k_div(const float* __restrict__ gsum, const int* __restrict__ gstart,
                      float* __restrict__ out) {
    int g = blockIdx.x;
    int c = threadIdx.x;  // 128
    float cnt = (float)(gstart[g + 1] - gstart[g]);
    out[g * HD + c] = gsum[g * HD + c] / fmaxf(cnt, 1.f);
}

// ---------------- launch ----------------
extern "C" void kernel_launch(void* const* d_in, const int* in_sizes, int n_in, void* d_out,
                              int out_size, void* d_ws, size_t ws_size, hipStream_t stream) {
    const float* x     = (const float*)d_in[0];
    const int* ei      = (const int*)d_in[1];
    const float* eattr = (const float*)d_in[2];
    const int* batch   = (const int*)d_in[3];
    const float* encW  = (const float*)d_in[4];
    const float* encB  = (const float*)d_in[5];
    const float* eW    = (const float*)d_in[6];
    const float* eB    = (const float*)d_in[7];
    const float* ln_g  = (const float*)d_in[8];
    const float* ln_b  = (const float*)d_in[9];
    const float* W1    = (const float*)d_in[10];
    const float* b1    = (const float*)d_in[11];
    const float* mlg   = (const float*)d_in[12];
    const float* mlb   = (const float*)d_in[13];
    const float* W2    = (const float*)d_in[14];
    const float* b2    = (const float*)d_in[15];
    const float* t     = (const float*)d_in[16];
    const int* src = ei;
    const int* dst = ei + NE;

    char* w = (char*)d_ws;
    auto alloc = [&](size_t bytes) {
        char* p = w;
        w += (bytes + 255) & ~size_t(255);
        return p;
    };
    unsigned short* h    = (unsigned short*)alloc(sizeof(unsigned short) * NN * HD);
    unsigned short* zb   = (unsigned short*)alloc(sizeof(unsigned short) * NN * HD);
    unsigned int* outb   = (unsigned int*)alloc(sizeof(unsigned int) * NN * HD / 2);
    float4* aperm        = (float4*)alloc(sizeof(float4) * NE);
    int* row_start       = (int*)alloc(sizeof(int) * (NN + 1));
    int* counts          = (int*)alloc(sizeof(int) * NN);
    int* cursor          = (int*)alloc(sizeof(int) * NN);
    int* incl            = (int*)alloc(sizeof(int) * NN);
    int* bsum            = (int*)alloc(sizeof(int) * 128);
    int* boff            = (int*)alloc(sizeof(int) * 128);
    int* gstart          = (int*)alloc(sizeof(int) * (NG + 1));
    float* gsum          = (float*)alloc(sizeof(float) * NG * HD);
    unsigned short* W1T  = (unsigned short*)alloc(sizeof(unsigned short) * NL * HD * HD2);
    unsigned short* W2T  = (unsigned short*)alloc(sizeof(unsigned short) * NL * HD2 * HD);

    hipMemsetAsync(counts, 0, sizeof(int) * NN, stream);
    hipMemsetAsync(cursor, 0, sizeof(int) * NN, stream);
    hipMemsetAsync(gsum, 0, sizeof(float) * NG * HD, stream);

    k_prep<<<512, 256, 0, stream>>>(W1, W2, W1T, W2T);
    k_encode_nodes<<<NN, HD, 0, stream>>>(x, encW, encB, zb);
    k_hist<<<(NE + 255) / 256, 256, 0, stream>>>(dst, counts);
    int nsb = (NN + SCAN_B - 1) / SCAN_B;
    k_scan1<<<nsb, SCAN_B, 0, stream>>>(counts, incl, bsum);
    k_scan2<<<1, 128, 0, stream>>>(bsum, boff, nsb);
    k_scan3<<<nsb, SCAN_B, 0, stream>>>(incl, boff, row_start);
    k_scatter<<<(NE + 255) / 256, 256, 0, stream>>>(src, dst, eattr, row_start, cursor, aperm);
    k_gbounds<<<(NG + 256) / 256, 256, 0, stream>>>(batch, gstart);

    for (int l = 0; l < NL; l++) {
        k_aggregate<<<(NN + 3) / 4, 256, 0, stream>>>(zb, aperm, row_start, eW, eB, t, l, outb);
        int ln_next = (l + 1) % NL;  // layer 3 fuses the final ln (reuses layer-0 params)
        k_mlp<<<(NN + BM - 1) / BM, 256, 0, stream>>>(
            (const unsigned short*)outb, W1T + (size_t)l * HD * HD2, b1 + l * HD2,
            mlg + l * HD2, mlb + l * HD2, W2T + (size_t)l * HD2 * HD, b2 + l * HD, h,
            ln_g + ln_next * HD, ln_b + ln_next * HD, zb, batch, gsum,
            l > 0, l < NL - 1, l == NL - 1);
    }
    k_div<<<NG, HD, 0, stream>>>(gsum, gstart, (float*)d_out);
}

// Round 7
// 484.297 us; speedup vs baseline: 1.1047x; 1.0360x over previous
//
#include <hip/hip_runtime.h>

#define NN 50000
#define NE 500000
#define HD 128
#define HD2 256
#define NL 4
#define NG 1000

constexpr float MSG_EPS = 1e-7f;
constexpr float LNEPS   = 1e-5f;

typedef float  f32x4  __attribute__((ext_vector_type(4)));
typedef __bf16 bf16x8 __attribute__((ext_vector_type(8)));

__device__ __forceinline__ unsigned short f2b(float f) {
    unsigned int u = __float_as_uint(f);
    unsigned int r = u + 0x7FFFu + ((u >> 16) & 1u);
    return (unsigned short)(r >> 16);
}
__device__ __forceinline__ float b2f(unsigned short h) {
    return __uint_as_float(((unsigned int)h) << 16);
}
__device__ __forceinline__ unsigned int pack2(float a, float b) {
    return (unsigned int)f2b(a) | ((unsigned int)f2b(b) << 16);
}

// ---------------- node encoder: z0 = bf16(x @ Wn + bn) ----------------
__global__ void k_encode_nodes(const float* __restrict__ x, const float* __restrict__ W,
                               const float* __restrict__ b, unsigned short* __restrict__ zb) {
    int n = blockIdx.x;
    int c = threadIdx.x;  // 128
    float xr[9];
#pragma unroll
    for (int k = 0; k < 9; k++) xr[k] = x[n * 9 + k];
    float acc = b[c];
#pragma unroll
    for (int k = 0; k < 9; k++) acc = fmaf(xr[k], W[k * HD + c], acc);
    zb[n * HD + c] = f2b(acc);
}

// ---------------- weight prep: fp32 -> bf16 transposed ----------------
__global__ void k_prep(const float* __restrict__ W1, const float* __restrict__ W2,
                       unsigned short* __restrict__ W1T, unsigned short* __restrict__ W2T) {
    int idx = blockIdx.x * 256 + threadIdx.x;  // 131072 total
    {
        int k = idx & 127, n = (idx >> 7) & 255, l = idx >> 15;
        W1T[idx] = f2b(W1[(l * 128 + k) * 256 + n]);
    }
    {
        int k = idx & 255, n = (idx >> 8) & 127, l = idx >> 15;
        W2T[idx] = f2b(W2[(l * 256 + k) * 128 + n]);
    }
}

// ---------------- CSR build ----------------
__global__ void k_hist(const int* __restrict__ dst, int* __restrict__ counts) {
    int e = blockIdx.x * blockDim.x + threadIdx.x;
    if (e < NE) atomicAdd(&counts[dst[e]], 1);
}

#define SCAN_B 512
__global__ void k_scan1(const int* __restrict__ counts, int* __restrict__ incl,
                        int* __restrict__ bsum) {
    __shared__ int s[SCAN_B];
    int i = blockIdx.x * SCAN_B + threadIdx.x;
    int v = (i < NN) ? counts[i] : 0;
    s[threadIdx.x] = v;
    __syncthreads();
    for (int off = 1; off < SCAN_B; off <<= 1) {
        int t = (threadIdx.x >= off) ? s[threadIdx.x - off] : 0;
        __syncthreads();
        s[threadIdx.x] += t;
        __syncthreads();
    }
    if (i < NN) incl[i] = s[threadIdx.x];
    if (threadIdx.x == SCAN_B - 1) bsum[blockIdx.x] = s[threadIdx.x];
}

__global__ void k_scan2(const int* __restrict__ bsum, int* __restrict__ boff, int nb) {
    __shared__ int s[128];
    int v = (threadIdx.x < nb) ? bsum[threadIdx.x] : 0;
    s[threadIdx.x] = v;
    __syncthreads();
    for (int off = 1; off < 128; off <<= 1) {
        int t = (threadIdx.x >= off) ? s[threadIdx.x - off] : 0;
        __syncthreads();
        s[threadIdx.x] += t;
        __syncthreads();
    }
    if (threadIdx.x < nb) boff[threadIdx.x] = s[threadIdx.x] - v;  // exclusive
}

__global__ void k_scan3(const int* __restrict__ incl, const int* __restrict__ boff,
                        int* __restrict__ row_start) {
    int i = blockIdx.x * SCAN_B + threadIdx.x;
    if (i < NN) row_start[i + 1] = incl[i] + boff[blockIdx.x];
    if (i == 0) row_start[0] = 0;
}

// pack {attr0, attr1, attr2, src<<6} per CSR slot (src premultiplied: z-row offset
// in uints, so the gather address is a single 32-bit add per edge)
__global__ void k_scatter(const int* __restrict__ src, const int* __restrict__ dst,
                          const float* __restrict__ eattr, const int* __restrict__ row_start,
                          int* __restrict__ cursor, float4* __restrict__ aperm) {
    int e = blockIdx.x * blockDim.x + threadIdx.x;
    if (e >= NE) return;
    int d = dst[e];
    int p = row_start[d] + atomicAdd(&cursor[d], 1);
    float4 v;
    v.x = eattr[e * 3 + 0];
    v.y = eattr[e * 3 + 1];
    v.z = eattr[e * 3 + 2];
    v.w = __int_as_float(src[e] << 6);
    aperm[p] = v;
}

// ---------------- per-edge softmax-agg accumulate (2 channels/lane) ----------------
__device__ __forceinline__ void edge_acc2(float4 a, unsigned int zz, float2 w0, float2 w1,
                                          float2 w2, float2 bb, float tv, float& num0,
                                          float& num1, float& wm0, float& wm1) {
    float zx = b2f((unsigned short)zz), zy = b2f((unsigned short)(zz >> 16));
    float eax = fmaf(a.x, w0.x, fmaf(a.y, w1.x, fmaf(a.z, w2.x, bb.x)));
    float eay = fmaf(a.x, w0.y, fmaf(a.y, w1.y, fmaf(a.z, w2.y, bb.y)));
    float mx = fmaxf(zx + eax, 0.f) + MSG_EPS;
    float my = fmaxf(zy + eay, 0.f) + MSG_EPS;
    float ex = __expf(tv * mx), ey = __expf(tv * my);
    num0 += ex;
    num1 += ey;
    wm0 = fmaf(mx, ex, wm0);
    wm1 = fmaf(my, ey, wm1);
}

// ---------------- softmax aggregation: one wave per node, 2 channels/lane ----------
// Software-pipelined edge loop (verified round-3 version): while the current 4-edge
// group's z-gathers are in flight, the NEXT group's aperm rows load.
__global__ __launch_bounds__(256) void k_aggregate(const unsigned short* __restrict__ zbin,
                                                   const float4* __restrict__ aperm,
                                                   const int* __restrict__ row_start,
                                                   const float* __restrict__ We,
                                                   const float* __restrict__ be,
                                                   const float* __restrict__ t, int layer,
                                                   unsigned int* __restrict__ outb) {
    int w = threadIdx.x >> 6, lane = threadIdx.x & 63;
    int n = blockIdx.x * 4 + w;
    if (n >= NN) return;
    int c = lane * 2;
    float2 w0 = *(const float2*)&We[c];
    float2 w1 = *(const float2*)&We[HD + c];
    float2 w2 = *(const float2*)&We[2 * HD + c];
    float2 bb = *(const float2*)&be[c];
    float tv = t[layer];
    int s0 = row_start[n], s1 = row_start[n + 1];
    const unsigned int* z32 = (const unsigned int*)zbin;
    unsigned int zn = z32[(size_t)n * 64 + lane];  // self row, early issue
    float num0 = 0.f, num1 = 0.f, wm0 = 0.f, wm1 = 0.f;
    int p = s0;
    if (p + 4 <= s1) {
        float4 A0 = aperm[p], A1 = aperm[p + 1], A2 = aperm[p + 2], A3 = aperm[p + 3];
        for (; p + 8 <= s1; p += 4) {
            unsigned int g0 = z32[(unsigned int)__float_as_int(A0.w) + lane];
            unsigned int g1 = z32[(unsigned int)__float_as_int(A1.w) + lane];
            unsigned int g2 = z32[(unsigned int)__float_as_int(A2.w) + lane];
            unsigned int g3 = z32[(unsigned int)__float_as_int(A3.w) + lane];
            float4 B0 = aperm[p + 4], B1 = aperm[p + 5], B2 = aperm[p + 6],
                   B3 = aperm[p + 7];
            edge_acc2(A0, g0, w0, w1, w2, bb, tv, num0, num1, wm0, wm1);
            edge_acc2(A1, g1, w0, w1, w2, bb, tv, num0, num1, wm0, wm1);
            edge_acc2(A2, g2, w0, w1, w2, bb, tv, num0, num1, wm0, wm1);
            edge_acc2(A3, g3, w0, w1, w2, bb, tv, num0, num1, wm0, wm1);
            A0 = B0;
            A1 = B1;
            A2 = B2;
            A3 = B3;
        }
        {  // last full group (guaranteed: p+4 <= s1 < p+8)
            unsigned int g0 = z32[(unsigned int)__float_as_int(A0.w) + lane];
            unsigned int g1 = z32[(unsigned int)__float_as_int(A1.w) + lane];
            unsigned int g2 = z32[(unsigned int)__float_as_int(A2.w) + lane];
            unsigned int g3 = z32[(unsigned int)__float_as_int(A3.w) + lane];
            edge_acc2(A0, g0, w0, w1, w2, bb, tv, num0, num1, wm0, wm1);
            edge_acc2(A1, g1, w0, w1, w2, bb, tv, num0, num1, wm0, wm1);
            edge_acc2(A2, g2, w0, w1, w2, bb, tv, num0, num1, wm0, wm1);
            edge_acc2(A3, g3, w0, w1, w2, bb, tv, num0, num1, wm0, wm1);
            p += 4;
        }
    }
    for (; p < s1; p++) {
        float4 a = aperm[p];
        unsigned int zz = z32[(unsigned int)__float_as_int(a.w) + lane];
        edge_acc2(a, zz, w0, w1, w2, bb, tv, num0, num1, wm0, wm1);
    }
    float ox = ((s1 > s0) ? (wm0 / num0) : 0.f) + b2f((unsigned short)zn);
    float oy = ((s1 > s0) ? (wm1 / num1) : 0.f) + b2f((unsigned short)(zn >> 16));
    outb[(size_t)n * 64 + lane] = pack2(ox, oy);
}

// ---------------- fused MFMA MLP + next-layer LN+relu (round-3 verified core) -------
// hnew = (add? h : 0) + relu(LN(A@W1+b1))@W2+b2 ; h=bf16(hnew); zb=bf16(relu(LN_next(hnew)))
// BM=32, 4 waves. Full A tile + residual h rows + epilogue LN params prefetched at entry.
// template<POOL>: POOL=false (layers 0..2) is EXACTLY the verified round-3 kernel
// (batch/gsum dead, no pool code in the epilogue -- compile-time specialization so the
// hot layers carry zero overhead). POOL=true (layer 3) replaces the zb store with the
// run-accumulated per-graph pool (batch sorted -> 1-3 transitions/wave, 2 fp32 atomics
// per wave-graph), killing the 12.8 MB zb write + 12.8 MB k_pool re-read.
#define BM 32
#define HS_LD 264  // bf16 row stride (256+8)
#define HT_LD 136  // bf16 row stride (128+8); as uint: 68

template <bool POOL>
__global__ __launch_bounds__(256) void k_mlp(const unsigned short* __restrict__ outb,
                                             const unsigned short* __restrict__ W1T,
                                             const float* __restrict__ b1l,
                                             const float* __restrict__ lgl,
                                             const float* __restrict__ lbl,
                                             const unsigned short* __restrict__ W2T,
                                             const float* __restrict__ b2l,
                                             unsigned short* __restrict__ h,
                                             const float* __restrict__ gn,
                                             const float* __restrict__ bn,
                                             unsigned short* __restrict__ zb,
                                             const int* __restrict__ batch,
                                             float* __restrict__ gsum,
                                             int add_residual, int store_h) {
    __shared__ __align__(16) unsigned short Hs[BM * HS_LD];  // 16896 B
    __shared__ __align__(16) unsigned short Ht[BM * HT_LD];  // 8704 B
    __shared__ __align__(16) float2 st1[2][16][4];           // 1024 B

    int nb = blockIdx.x * BM;
    int tid = threadIdx.x;
    int w = tid >> 6, lane = tid & 63, q = lane >> 4, i = lane & 15;

    // ---- full A prefetch: all 8 fragments issue NOW (32 VGPR) ----
    bf16x8 areg[2][4];
#pragma unroll
    for (int rt = 0; rt < 2; rt++) {
        int row = nb + rt * 16 + i;
#pragma unroll
        for (int ks = 0; ks < 4; ks++)
            areg[rt][ks] = (row < NN)
                               ? *(const bf16x8*)&outb[(size_t)row * HD + ks * 32 + q * 8]
                               : (bf16x8)(__bf16)0.f;
    }

    // ---- epilogue prefetch: residual h rows + final-LN params ----
    unsigned int hv[8];
    const unsigned int* h32c = (const unsigned int*)h;
    if (add_residual) {
#pragma unroll
        for (int it = 0; it < 8; it++) {
            int row = nb + w + it * 4;
            hv[it] = (row < NN) ? h32c[(size_t)row * 64 + lane] : 0u;
        }
    } else {
#pragma unroll
        for (int it = 0; it < 8; it++) hv[it] = 0u;
    }
    float2 gg = *(const float2*)&gn[lane * 2];
    float2 cc = *(const float2*)&bn[lane * 2];

    // ---- GEMM1: 32x256, K=128; A in registers, B 1-step lookahead ----
    f32x4 acc[2][4];
#pragma unroll
    for (int rt = 0; rt < 2; rt++)
#pragma unroll
        for (int ct = 0; ct < 4; ct++) acc[rt][ct] = (f32x4){0.f, 0.f, 0.f, 0.f};

    bf16x8 bcur[4];
#pragma unroll
    for (int ct = 0; ct < 4; ct++)
        bcur[ct] = *(const bf16x8*)&W1T[(w * 64 + ct * 16 + i) * HD + q * 8];

#pragma unroll
    for (int ks = 0; ks < 4; ks++) {
        bf16x8 bnxt[4];
        if (ks < 3) {
#pragma unroll
            for (int ct = 0; ct < 4; ct++)
                bnxt[ct] =
                    *(const bf16x8*)&W1T[(w * 64 + ct * 16 + i) * HD + (ks + 1) * 32 + q * 8];
        }
#pragma unroll
        for (int rt = 0; rt < 2; rt++)
#pragma unroll
            for (int ct = 0; ct < 4; ct++)
                acc[rt][ct] = __builtin_amdgcn_mfma_f32_16x16x32_bf16(areg[rt][ks], bcur[ct],
                                                                     acc[rt][ct], 0, 0, 0);
        if (ks < 3) {
#pragma unroll
            for (int ct = 0; ct < 4; ct++) bcur[ct] = bnxt[ct];
        }
    }

    // ---- +b1 ----
#pragma unroll
    for (int ct = 0; ct < 4; ct++) {
        float bb = b1l[w * 64 + ct * 16 + i];
#pragma unroll
        for (int rt = 0; rt < 2; rt++)
#pragma unroll
            for (int r = 0; r < 4; r++) acc[rt][ct][r] += bb;
    }

    // ---- LN(256) stats in-register + cross-wave exchange ----
    {
        float sv[2][4], qv[2][4];
#pragma unroll
        for (int rt = 0; rt < 2; rt++)
#pragma unroll
            for (int r = 0; r < 4; r++) {
                float s = acc[rt][0][r] + acc[rt][1][r] + acc[rt][2][r] + acc[rt][3][r];
                float sq = 0.f;
#pragma unroll
                for (int ct = 0; ct < 4; ct++) sq = fmaf(acc[rt][ct][r], acc[rt][ct][r], sq);
                sv[rt][r] = s;
                qv[rt][r] = sq;
            }
#pragma unroll
        for (int m = 1; m <= 8; m <<= 1)
#pragma unroll
            for (int rt = 0; rt < 2; rt++)
#pragma unroll
                for (int r = 0; r < 4; r++) {
                    sv[rt][r] += __shfl_xor(sv[rt][r], m);
                    qv[rt][r] += __shfl_xor(qv[rt][r], m);
                }
        if (i == 0) {
#pragma unroll
            for (int rt = 0; rt < 2; rt++)
#pragma unroll
                for (int r = 0; r < 4; r++)
                    st1[rt][q * 4 + r][w] = make_float2(sv[rt][r], qv[rt][r]);
        }
    }
    __syncthreads();

    {
        float mu[2][4], inv[2][4];
#pragma unroll
        for (int rt = 0; rt < 2; rt++)
#pragma unroll
            for (int r = 0; r < 4; r++) {
                const float4* sp = (const float4*)&st1[rt][q * 4 + r][0];
                float4 a = sp[0], b = sp[1];
                float S = a.x + a.z + b.x + b.z;
                float Q = a.y + a.w + b.y + b.w;
                float m_ = S * (1.f / 256.f);
                float v_ = Q * (1.f / 256.f) - m_ * m_;
                mu[rt][r] = m_;
                inv[rt][r] = rsqrtf(v_ + LNEPS);
            }
#pragma unroll
        for (int ct = 0; ct < 4; ct++) {
            float g = lgl[w * 64 + ct * 16 + i];
            float c = lbl[w * 64 + ct * 16 + i];
#pragma unroll
            for (int rt = 0; rt < 2; rt++)
#pragma unroll
                for (int r = 0; r < 4; r++) {
                    float v =
                        fmaxf(fmaf((acc[rt][ct][r] - mu[rt][r]) * inv[rt][r], g, c), 0.f);
                    Hs[(rt * 16 + q * 4 + r) * HS_LD + w * 64 + ct * 16 + i] = f2b(v);
                }
        }
    }
    __syncthreads();

    // ---- GEMM2: 32x128, K=256; A from Hs, 1-step lookahead ----
    f32x4 acc2[2][2];
#pragma unroll
    for (int rt = 0; rt < 2; rt++)
#pragma unroll
        for (int ct = 0; ct < 2; ct++) acc2[rt][ct] = (f32x4){0.f, 0.f, 0.f, 0.f};

    bf16x8 hc[2], bc[2];
#pragma unroll
    for (int rt = 0; rt < 2; rt++) hc[rt] = *(const bf16x8*)&Hs[(rt * 16 + i) * HS_LD + q * 8];
#pragma unroll
    for (int ct = 0; ct < 2; ct++)
        bc[ct] = *(const bf16x8*)&W2T[(w * 32 + ct * 16 + i) * HD2 + q * 8];

#pragma unroll
    for (int ks = 0; ks < 8; ks++) {
        bf16x8 hn[2], bn2[2];
        if (ks < 7) {
#pragma unroll
            for (int rt = 0; rt < 2; rt++)
                hn[rt] = *(const bf16x8*)&Hs[(rt * 16 + i) * HS_LD + (ks + 1) * 32 + q * 8];
#pragma unroll
            for (int ct = 0; ct < 2; ct++)
                bn2[ct] =
                    *(const bf16x8*)&W2T[(w * 32 + ct * 16 + i) * HD2 + (ks + 1) * 32 + q * 8];
        }
#pragma unroll
        for (int rt = 0; rt < 2; rt++)
#pragma unroll
            for (int ct = 0; ct < 2; ct++)
                acc2[rt][ct] = __builtin_amdgcn_mfma_f32_16x16x32_bf16(hc[rt], bc[ct],
                                                                      acc2[rt][ct], 0, 0, 0);
        if (ks < 7) {
#pragma unroll
            for (int rt = 0; rt < 2; rt++) hc[rt] = hn[rt];
#pragma unroll
            for (int ct = 0; ct < 2; ct++) bc[ct] = bn2[ct];
        }
    }

    // ---- conv-out (+b2) -> bf16 LDS tile Ht (C-layout scatter; LDS absorbs it) ----
#pragma unroll
    for (int ct = 0; ct < 2; ct++) {
        float bb = b2l[w * 32 + ct * 16 + i];
#pragma unroll
        for (int rt = 0; rt < 2; rt++)
#pragma unroll
            for (int r = 0; r < 4; r++)
                Ht[(rt * 16 + q * 4 + r) * HT_LD + w * 32 + ct * 16 + i] =
                    f2b(acc2[rt][ct][r] + bb);
    }
    __syncthreads();

    // ---- row-wise COALESCED epilogue ----
    {
        const unsigned int* Ht32 = (const unsigned int*)Ht;
        unsigned int* h32 = (unsigned int*)h;
        unsigned int* zb32 = (unsigned int*)zb;
        int gc = -1;
        float a0 = 0.f, a1 = 0.f;
#pragma unroll
        for (int it = 0; it < 8; it++) {
            int rr = w + it * 4;
            int row = nb + rr;
            unsigned int tv = Ht32[rr * (HT_LD / 2) + lane];
            float cx = b2f((unsigned short)tv) + b2f((unsigned short)hv[it]);
            float cy = b2f((unsigned short)(tv >> 16)) + b2f((unsigned short)(hv[it] >> 16));
            float s = cx + cy, sq = cx * cx + cy * cy;
#pragma unroll
            for (int m = 32; m >= 1; m >>= 1) {
                s += __shfl_xor(s, m);
                sq += __shfl_xor(sq, m);
            }
            float mu = s * (1.f / 128.f);
            float var = sq * (1.f / 128.f) - mu * mu;
            float inv = rsqrtf(var + LNEPS);
            float z0 = fmaxf(fmaf((cx - mu) * inv, gg.x, cc.x), 0.f);
            float z1 = fmaxf(fmaf((cy - mu) * inv, gg.y, cc.y), 0.f);
            if (row < NN) {
                if (!POOL) {
                    if (store_h) h32[(size_t)row * 64 + lane] = pack2(cx, cy);
                    zb32[(size_t)row * 64 + lane] = pack2(z0, z1);
                } else {
                    int g = batch[row];  // wave-uniform (row depends on w, it only)
                    if (g != gc) {
                        if (gc >= 0) {
                            atomicAdd(&gsum[gc * HD + lane * 2], a0);
                            atomicAdd(&gsum[gc * HD + lane * 2 + 1], a1);
                        }
                        gc = g;
                        a0 = 0.f;
                        a1 = 0.f;
                    }
                    a0 += z0;
                    a1 += z1;
                }
            }
        }
        if (POOL && gc >= 0) {
            atomicAdd(&gsum[gc * HD + lane * 2], a0);
            atomicAdd(&gsum[gc * HD + lane * 2 + 1], a1);
        }
    }
}

// ---------------- graph bounds (batch is sorted) ----------------
__global__ void k_gbounds(const int* __restrict__ batch, int* __restrict__ gstart) {
    int g = blockIdx.x * blockDim.x + threadIdx.x;
    if (g > NG) return;
    int lo = 0, hi = NN;
    while (lo < hi) {
        int mid = (lo + hi) >> 1;
        if (batch[mid] < g) lo = mid + 1;
        else hi = mid;
    }
    gstart[g] = lo;
}

// ---------------- final divide: out = gsum / count ----------------
__global__ void k_div(const float* __restrict__ gsum, const int* __restrict__ gstart,
                      float* __restrict__ out) {
    int g = blockIdx.x;
    int c = threadIdx.x;  // 128
    float cnt = (float)(gstart[g + 1] - gstart[g]);
    out[g * HD + c] = gsum[g * HD + c] / fmaxf(cnt, 1.f);
}

// ---------------- launch ----------------
extern "C" void kernel_launch(void* const* d_in, const int* in_sizes, int n_in, void* d_out,
                              int out_size, void* d_ws, size_t ws_size, hipStream_t stream) {
    const float* x     = (const float*)d_in[0];
    const int* ei      = (const int*)d_in[1];
    const float* eattr = (const float*)d_in[2];
    const int* batch   = (const int*)d_in[3];
    const float* encW  = (const float*)d_in[4];
    const float* encB  = (const float*)d_in[5];
    const float* eW    = (const float*)d_in[6];
    const float* eB    = (const float*)d_in[7];
    const float* ln_g  = (const float*)d_in[8];
    const float* ln_b  = (const float*)d_in[9];
    const float* W1    = (const float*)d_in[10];
    const float* b1    = (const float*)d_in[11];
    const float* mlg   = (const float*)d_in[12];
    const float* mlb   = (const float*)d_in[13];
    const float* W2    = (const float*)d_in[14];
    const float* b2    = (const float*)d_in[15];
    const float* t     = (const float*)d_in[16];
    const int* src = ei;
    const int* dst = ei + NE;

    char* w = (char*)d_ws;
    auto alloc = [&](size_t bytes) {
        char* p = w;
        w += (bytes + 255) & ~size_t(255);
        return p;
    };
    unsigned short* h    = (unsigned short*)alloc(sizeof(unsigned short) * NN * HD);
    unsigned short* zb   = (unsigned short*)alloc(sizeof(unsigned short) * NN * HD);
    unsigned int* outb   = (unsigned int*)alloc(sizeof(unsigned int) * NN * HD / 2);
    float4* aperm        = (float4*)alloc(sizeof(float4) * NE);
    int* row_start       = (int*)alloc(sizeof(int) * (NN + 1));
    int* counts          = (int*)alloc(sizeof(int) * NN);
    int* cursor          = (int*)alloc(sizeof(int) * NN);
    int* incl            = (int*)alloc(sizeof(int) * NN);
    int* bsum            = (int*)alloc(sizeof(int) * 128);
    int* boff            = (int*)alloc(sizeof(int) * 128);
    int* gstart          = (int*)alloc(sizeof(int) * (NG + 1));
    float* gsum          = (float*)alloc(sizeof(float) * NG * HD);
    unsigned short* W1T  = (unsigned short*)alloc(sizeof(unsigned short) * NL * HD * HD2);
    unsigned short* W2T  = (unsigned short*)alloc(sizeof(unsigned short) * NL * HD2 * HD);

    hipMemsetAsync(counts, 0, sizeof(int) * NN, stream);
    hipMemsetAsync(cursor, 0, sizeof(int) * NN, stream);
    hipMemsetAsync(gsum, 0, sizeof(float) * NG * HD, stream);

    k_prep<<<512, 256, 0, stream>>>(W1, W2, W1T, W2T);
    k_encode_nodes<<<NN, HD, 0, stream>>>(x, encW, encB, zb);
    k_hist<<<(NE + 255) / 256, 256, 0, stream>>>(dst, counts);
    int nsb = (NN + SCAN_B - 1) / SCAN_B;
    k_scan1<<<nsb, SCAN_B, 0, stream>>>(counts, incl, bsum);
    k_scan2<<<1, 128, 0, stream>>>(bsum, boff, nsb);
    k_scan3<<<nsb, SCAN_B, 0, stream>>>(incl, boff, row_start);
    k_scatter<<<(NE + 255) / 256, 256, 0, stream>>>(src, dst, eattr, row_start, cursor, aperm);
    k_gbounds<<<(NG + 256) / 256, 256, 0, stream>>>(batch, gstart);

    int nblk = (NN + BM - 1) / BM;
    for (int l = 0; l < NL; l++) {
        k_aggregate<<<(NN + 3) / 4, 256, 0, stream>>>(zb, aperm, row_start, eW, eB, t, l, outb);
        int ln_next = (l + 1) % NL;  // layer 3 fuses the final ln (reuses layer-0 params)
        if (l < NL - 1) {
            k_mlp<false><<<nblk, 256, 0, stream>>>(
                (const unsigned short*)outb, W1T + (size_t)l * HD * HD2, b1 + l * HD2,
                mlg + l * HD2, mlb + l * HD2, W2T + (size_t)l * HD2 * HD, b2 + l * HD, h,
                ln_g + ln_next * HD, ln_b + ln_next * HD, zb, batch, gsum, l > 0, 1);
        } else {
            k_mlp<true><<<nblk, 256, 0, stream>>>(
                (const unsigned short*)outb, W1T + (size_t)l * HD * HD2, b1 + l * HD2,
                mlg + l * HD2, mlb + l * HD2, W2T + (size_t)l * HD2 * HD, b2 + l * HD, h,
                ln_g + ln_next * HD, ln_b + ln_next * HD, zb, batch, gsum, 1, 0);
        }
    }
    k_div<<<NG, HD, 0, stream>>>(gsum, gstart, (float*)d_out);
}